// Round 2
// baseline (2873.617 us; speedup 1.0000x reference)
//
#include <hip/hip_runtime.h>
#include <math.h>

constexpr int C_B = 2, C_S = 1024, C_D = 512, C_H = 8, C_DH = 64,
              C_F = 2048, C_L = 6, C_V = 32000;
constexpr float C_EPS = 1e-6f;

using bf16x8 = __attribute__((ext_vector_type(8))) __bf16;
using bf16x4v = __attribute__((ext_vector_type(4))) __bf16;
using f32x4  = __attribute__((ext_vector_type(4))) float;

__device__ __forceinline__ f32x4 mfma16(bf16x8 a, bf16x8 b, f32x4 c) {
  return __builtin_amdgcn_mfma_f32_16x16x32_bf16(a, b, c, 0, 0, 0);
}

__device__ __forceinline__ void async16(const __bf16* g, __bf16* l) {
  __builtin_amdgcn_global_load_lds(
      (const __attribute__((address_space(1))) void*)g,
      (__attribute__((address_space(3))) void*)l, 16, 0, 0);
}

__device__ __forceinline__ float block_sum(float v, float* sbuf) {
#pragma unroll
  for (int o = 32; o > 0; o >>= 1) v += __shfl_down(v, o);
  __syncthreads();
  if ((threadIdx.x & 63) == 0) sbuf[threadIdx.x >> 6] = v;
  __syncthreads();
  return (sbuf[0] + sbuf[1]) + (sbuf[2] + sbuf[3]);
}

// ---------------------------------------------------------------------------
// bf16 GEMM, B in [N][K] layout. C[M,N] = scale*(A@B^T) + bias, epilogues:
// EPI 0: store bf16; 1: store bf16+relu; 3: store f32; 4: f32 atomicAdd
// (residual, bias only when zb==0; z = K-split index via sAb/sBb k-offsets).
// TRI: bias segmented per 512 cols (b0/b1/b2). SWAP: m from blockIdx.x.
// global_load_lds staging (16B/lane), XOR granule swizzle in LDS.
// ---------------------------------------------------------------------------
template <int BM, int BN, int EPI, bool TRI, bool SWAP>
__global__ __launch_bounds__(256) void gemm_bt(
    const __bf16* __restrict__ A, int lda, long sAb, long sAh,
    const __bf16* __restrict__ B, int ldb, long sBb, long sBh,
    void* __restrict__ Cv, int ldc, long sCb, long sCh,
    const float* __restrict__ b0, const float* __restrict__ b1,
    const float* __restrict__ b2, int K, int hdim, float scale) {
  constexpr int BK = 32;
  __shared__ __bf16 As[BM][BK];
  __shared__ __bf16 Bs[BN][BK];
  const int z = blockIdx.z;
  const int zb = z / hdim, zh = z - zb * hdim;
  const __bf16* Ap = A + (long)zb * sAb + (long)zh * sAh;
  const __bf16* Bp = B + (long)zb * sBb + (long)zh * sBh;
  const int m0 = (SWAP ? blockIdx.x : blockIdx.y) * BM;
  const int n0 = (SWAP ? blockIdx.y : blockIdx.x) * BN;
  const int t = threadIdx.x, lane = t & 63, w = t >> 6;
  const int wr = w >> 1, wc = w & 1;
  constexpr int WM = BM / 2, WN = BN / 2, TM = WM / 16, TN = WN / 16;
  constexpr int AI = BM / 64, BI = BN / 64;
  const int srow = lane >> 2;       // row within 16-row staging group
  const int sg = lane & 3;          // LDS granule this lane fills
  const int fr = lane & 15, fq = lane >> 4;

  f32x4 acc[TM][TN] = {};
  for (int k0 = 0; k0 < K; k0 += BK) {
#pragma unroll
    for (int j = 0; j < AI; ++j) {
      const int r0 = w * (AI * 16) + j * 16;
      const int row = r0 + srow;
      const int s = sg ^ ((row >> 1) & 3);  // global k-seg for this granule
      async16(Ap + (long)(m0 + row) * lda + (k0 + s * 8), &As[r0][0]);
    }
#pragma unroll
    for (int j = 0; j < BI; ++j) {
      const int r0 = w * (BI * 16) + j * 16;
      const int row = r0 + srow;
      const int s = sg ^ ((row >> 1) & 3);
      async16(Bp + (long)(n0 + row) * ldb + (k0 + s * 8), &Bs[r0][0]);
    }
    __syncthreads();
    bf16x8 af[TM], bfr[TN];
#pragma unroll
    for (int i = 0; i < TM; ++i) {
      const int row = wr * WM + i * 16 + fr;
      const int g = fq ^ ((row >> 1) & 3);
      af[i] = *(const bf16x8*)&As[row][g * 8];
    }
#pragma unroll
    for (int i = 0; i < TN; ++i) {
      const int row = wc * WN + i * 16 + fr;
      const int g = fq ^ ((row >> 1) & 3);
      bfr[i] = *(const bf16x8*)&Bs[row][g * 8];
    }
#pragma unroll
    for (int i = 0; i < TM; ++i)
#pragma unroll
      for (int j = 0; j < TN; ++j) acc[i][j] = mfma16(af[i], bfr[j], acc[i][j]);
    __syncthreads();
  }

  const long co = (long)zb * sCb + (long)zh * sCh;
  const int rq = (lane >> 4) * 4;
#pragma unroll
  for (int i = 0; i < TM; ++i) {
#pragma unroll
    for (int j = 0; j < TN; ++j) {
      const int colg = n0 + wc * WN + j * 16 + fr;
      float bv = 0.f;
      if (b0) {
        if (TRI) {
          const float* bp = colg < 512 ? b0 : (colg < 1024 ? b1 : b2);
          bv = bp[colg & 511];
        } else {
          bv = b0[colg];
        }
      }
      if (EPI == 4 && zb != 0) bv = 0.f;
#pragma unroll
      for (int r = 0; r < 4; ++r) {
        const int rowg = m0 + wr * WM + i * 16 + rq + r;
        const long ci = co + (long)rowg * ldc + colg;
        float v = acc[i][j][r] * scale + bv;
        if (EPI == 0) ((__bf16*)Cv)[ci] = (__bf16)v;
        else if (EPI == 1) ((__bf16*)Cv)[ci] = (__bf16)fmaxf(v, 0.f);
        else if (EPI == 3) ((float*)Cv)[ci] = v;
        else atomicAdd((float*)Cv + ci, v);
      }
    }
  }
}

// ---------------------------------------------------------------------------
// Fused flash attention. qkv[b*S+s][1536] (Q|K|V, h*64+dh within each 512),
// vT[(b*8+h)][dh][s]. Output ob[b*S+s][h*64+dh] bf16.
// Grid: x = q-tile (64 rows), y = b*8+h. 4 waves, wave w owns q-rows
// [qt*64+w*16, +16). K/V fragments read direct from global (L1/L2-resident).
// P transits wave-private LDS with gemm_bt's granule XOR swizzle.
// MODE 0: key mask from src_mask[b][k]. MODE 1: analytic causal (tril).
// ---------------------------------------------------------------------------
template <int MODE>
__global__ __launch_bounds__(256) void flash_attn(
    const __bf16* __restrict__ qkv, const __bf16* __restrict__ vT,
    const int* __restrict__ mask, __bf16* __restrict__ ob) {
  __shared__ __bf16 Pl[4][16][64];
  const int z = blockIdx.y, b = z >> 3, h = z & 7;
  const int qt = blockIdx.x, q0 = qt * 64;
  const int t = threadIdx.x, lane = t & 63, w = t >> 6;
  const int fr = lane & 15, fq = lane >> 4;
  const int qrow = q0 + w * 16;

  // Q fragments (row = fr, k-dim granule = fq*8, 2 chunks of 32 over D=64)
  const __bf16* qbase = qkv + ((long)(b << 10) + qrow + fr) * 1536 + h * 64;
  const bf16x8 qf0 = *(const bf16x8*)(qbase + fq * 8);
  const bf16x8 qf1 = *(const bf16x8*)(qbase + 32 + fq * 8);
  const __bf16* kbase = qkv + (long)(b << 10) * 1536 + 512 + h * 64;
  const __bf16* vbase = vT + (long)z * 64 * 1024;

  f32x4 oacc[4] = {};
  float m[4], l[4];
#pragma unroll
  for (int r = 0; r < 4; ++r) { m[r] = -3e38f; l[r] = 0.f; }
  const int myq = qrow + fq * 4;  // C-layout row base for this lane

  const int nkv = (MODE == 1) ? (qt + 1) : 16;
  for (int kt = 0; kt < nkv; ++kt) {
    const int k0 = kt * 64;
    // ---- S = Q K^T ----
    f32x4 sc[4] = {};
#pragma unroll
    for (int j = 0; j < 4; ++j) {
      const __bf16* kp = kbase + (long)(k0 + j * 16 + fr) * 1536;
      const bf16x8 kf0 = *(const bf16x8*)(kp + fq * 8);
      const bf16x8 kf1 = *(const bf16x8*)(kp + 32 + fq * 8);
      sc[j] = mfma16(qf0, kf0, sc[j]);
      sc[j] = mfma16(qf1, kf1, sc[j]);
    }
    // ---- mask + scale ----
    float sv[4][4];
    if (MODE == 0) {
#pragma unroll
      for (int j = 0; j < 4; ++j) {
        const int km = mask[(b << 10) + k0 + j * 16 + fr];
#pragma unroll
        for (int r = 0; r < 4; ++r)
          sv[j][r] = km != 0 ? sc[j][r] * 0.125f : -1e9f;
      }
    } else {
#pragma unroll
      for (int j = 0; j < 4; ++j) {
        const int kpos = k0 + j * 16 + fr;
#pragma unroll
        for (int r = 0; r < 4; ++r)
          sv[j][r] = kpos <= myq + r ? sc[j][r] * 0.125f : -1e9f;
      }
    }
    // ---- online softmax (rows live across the 16-lane fr dimension) ----
    float p[4][4];
#pragma unroll
    for (int r = 0; r < 4; ++r) {
      float tm = fmaxf(fmaxf(sv[0][r], sv[1][r]), fmaxf(sv[2][r], sv[3][r]));
#pragma unroll
      for (int o = 8; o > 0; o >>= 1) tm = fmaxf(tm, __shfl_xor(tm, o));
      const float mn = fmaxf(m[r], tm);
      const float corr = __expf(m[r] - mn);
      m[r] = mn;
      float rs = 0.f;
#pragma unroll
      for (int j = 0; j < 4; ++j) { p[j][r] = __expf(sv[j][r] - mn); rs += p[j][r]; }
#pragma unroll
      for (int o = 8; o > 0; o >>= 1) rs += __shfl_xor(rs, o);
      l[r] = l[r] * corr + rs;
#pragma unroll
      for (int j = 0; j < 4; ++j) oacc[j][r] *= corr;
    }
    // ---- P -> LDS (granule XOR swizzle, wave-private: no barrier) ----
    __bf16* pw = &Pl[w][0][0];
#pragma unroll
    for (int j = 0; j < 4; ++j) {
      const int c = j >> 1;
      const int gc = (2 * j + (fr >> 3)) & 3;
      const int e = fr & 7;
#pragma unroll
      for (int r = 0; r < 4; ++r) {
        const int row = fq * 4 + r;
        const int slot = c * 4 + (gc ^ ((row >> 1) & 3));
        pw[row * 64 + slot * 8 + e] = (__bf16)p[j][r];
      }
    }
    // ---- O += P V ----
#pragma unroll
    for (int c = 0; c < 2; ++c) {
      const int slot = c * 4 + (fq ^ ((fr >> 1) & 3));
      const bf16x8 pa = *(const bf16x8*)&Pl[w][fr][slot * 8];
#pragma unroll
      for (int j = 0; j < 4; ++j) {
        const bf16x8 vf = *(const bf16x8*)(vbase + (long)(j * 16 + fr) * 1024 +
                                           k0 + c * 32 + fq * 8);
        oacc[j] = mfma16(pa, vf, oacc[j]);
      }
    }
  }

  // ---- finalize: O / l, store bf16 ----
  float inv[4];
#pragma unroll
  for (int r = 0; r < 4; ++r) inv[r] = 1.0f / l[r];
  __bf16* obase = ob + ((long)(b << 10) + myq) * 512 + h * 64;
#pragma unroll
  for (int j = 0; j < 4; ++j)
#pragma unroll
    for (int r = 0; r < 4; ++r)
      obase[(long)r * 512 + j * 16 + fr] = (__bf16)(oacc[j][r] * inv[r]);
}

// ---------------------------------------------------------------------------
// transpose + f32->bf16: in [z][R][C] f32 -> out [z][C][R] bf16 (+outOff)
// ---------------------------------------------------------------------------
__global__ __launch_bounds__(256) void transpose_cvt(
    const float* __restrict__ in, __bf16* __restrict__ out, int R, int C,
    long inS, long outS, long outOff) {
  __shared__ __bf16 tile[32][33];
  in += (long)blockIdx.z * inS;
  out += (long)blockIdx.z * outS + outOff;
  const int c0 = blockIdx.x * 32, r0 = blockIdx.y * 32;
  const int tc = threadIdx.x & 31, tr = threadIdx.x >> 5;  // 8 rows/pass
#pragma unroll
  for (int j = 0; j < 32; j += 8)
    tile[tr + j][tc] = (__bf16)in[(long)(r0 + tr + j) * C + (c0 + tc)];
  __syncthreads();
#pragma unroll
  for (int j = 0; j < 32; j += 8)
    out[(long)(c0 + tr + j) * R + (r0 + tc)] = tile[tc][tr + j];
}

// ---------------------------------------------------------------------------
// V transpose: qkv[b*S+s][1024 + h*64 + dh] -> vT[(b*8+h)*64 + dh][s]
// ---------------------------------------------------------------------------
__global__ __launch_bounds__(256) void vtrans_kernel(
    const __bf16* __restrict__ qkv, __bf16* __restrict__ vT) {
  __shared__ __bf16 tile[32][33];
  const int z = blockIdx.z, b = z >> 3, h = z & 7;
  const int s0 = blockIdx.x * 32, d0 = blockIdx.y * 32;
  const int tc = threadIdx.x & 31, tr = threadIdx.x >> 5;
  const __bf16* src = qkv + (long)(b << 10) * 1536 + 1024 + h * 64;
#pragma unroll
  for (int j = 0; j < 32; j += 8)
    tile[tr + j][tc] = src[(long)(s0 + tr + j) * 1536 + (d0 + tc)];
  __syncthreads();
  __bf16* dst = vT + (long)z * 64 * 1024;
#pragma unroll
  for (int j = 0; j < 32; j += 8)
    dst[(long)(d0 + tr + j) * 1024 + (s0 + tc)] = tile[tc][tr + j];
}

// ---------------------------------------------------------------------------
__global__ __launch_bounds__(256) void embed_kernel(
    const int* __restrict__ tok, const float* __restrict__ emb,
    float* __restrict__ out) {
  const int bs = blockIdx.x;
  const int spos = bs & (C_S - 1);
  const int tk = tok[bs];
  const float* ep = emb + (long)tk * C_D;
  float* op = out + (long)bs * C_D;
  for (int d = threadIdx.x; d < C_D; d += 256) {
    const int i2 = d & ~1;
    const float freq = __expf((float)i2 * (-9.210340371976184f / 512.0f));
    const float ang = (float)spos * freq;
    const float pe = (d & 1) ? cosf(ang) : sinf(ang);
    op[d] = ep[d] * 22.62741699796952f + pe;
  }
}

__global__ __launch_bounds__(256) void ln_kernel(const float* __restrict__ x,
                                                 __bf16* __restrict__ out) {
  __shared__ float sbuf[4];
  const long row = blockIdx.x;
  const float* xp = x + row * C_D;
  __bf16* op = out + row * C_D;
  const int t = threadIdx.x;
  const float v0 = xp[t];
  const float v1 = xp[t + 256];
  const float mean = block_sum(v0 + v1, sbuf) * (1.0f / 512.0f);
  const float d0 = v0 - mean, d1 = v1 - mean;
  const float ss = block_sum(d0 * d0 + d1 * d1, sbuf);
  const float stdv = sqrtf(ss * (1.0f / 511.0f));
  const float inv = 1.0f / (stdv + C_EPS);
  op[t] = (__bf16)(d0 * inv);
  op[t + 256] = (__bf16)(d1 * inv);
}

// ---------------------------------------------------------------------------
// log_softmax over rows of V=32000 f32, in-place.
// float4 loads (16B/lane), dual online (m,l) states to break the serial
// exp-dependence chain, fully unrolled so loads batch under one vmcnt window.
// Row = 31 float4 iters (31744 elems) + 256-elem scalar tail.
// ---------------------------------------------------------------------------
__global__ __launch_bounds__(256) void logsoftmax_kernel(float* __restrict__ out) {
  __shared__ float sm[4], sl[4];
  const long row = blockIdx.x;
  float* p = out + row * C_V;
  const int t = threadIdx.x, lane = t & 63, w = t >> 6;
  float m0 = -1e30f, l0 = 0.f, m1 = -1e30f, l1 = 0.f;
#pragma unroll
  for (int i = 0; i < 30; i += 2) {
    const f32x4 a = *(const f32x4*)(p + (long)i * 1024 + t * 4);
    const f32x4 b = *(const f32x4*)(p + (long)(i + 1) * 1024 + t * 4);
    {
      const float mx = fmaxf(fmaxf(a[0], a[1]), fmaxf(a[2], a[3]));
      const float mn = fmaxf(m0, mx);
      l0 = l0 * __expf(m0 - mn) +
           ((__expf(a[0] - mn) + __expf(a[1] - mn)) +
            (__expf(a[2] - mn) + __expf(a[3] - mn)));
      m0 = mn;
    }
    {
      const float mx = fmaxf(fmaxf(b[0], b[1]), fmaxf(b[2], b[3]));
      const float mn = fmaxf(m1, mx);
      l1 = l1 * __expf(m1 - mn) +
           ((__expf(b[0] - mn) + __expf(b[1] - mn)) +
            (__expf(b[2] - mn) + __expf(b[3] - mn)));
      m1 = mn;
    }
  }
  {  // vector iter 30
    const f32x4 a = *(const f32x4*)(p + (long)30 * 1024 + t * 4);
    const float mx = fmaxf(fmaxf(a[0], a[1]), fmaxf(a[2], a[3]));
    const float mn = fmaxf(m0, mx);
    l0 = l0 * __expf(m0 - mn) +
         ((__expf(a[0] - mn) + __expf(a[1] - mn)) +
          (__expf(a[2] - mn) + __expf(a[3] - mn)));
    m0 = mn;
  }
  {  // scalar tail: elements 31744..31999
    const float v = p[31744 + t];
    const float mn = fmaxf(m1, v);
    l1 = l1 * __expf(m1 - mn) + __expf(v - mn);
    m1 = mn;
  }
  // merge dual states
  float m = fmaxf(m0, m1);
  float l = l0 * __expf(m0 - m) + l1 * __expf(m1 - m);
#pragma unroll
  for (int o = 32; o > 0; o >>= 1) {
    const float m2 = __shfl_down(m, o), l2 = __shfl_down(l, o);
    const float M = fmaxf(m, m2);
    l = l * __expf(m - M) + l2 * __expf(m2 - M);
    m = M;
  }
  if (lane == 0) { sm[w] = m; sl[w] = l; }
  __syncthreads();
  const float M = fmaxf(fmaxf(sm[0], sm[1]), fmaxf(sm[2], sm[3]));
  const float L = sl[0] * __expf(sm[0] - M) + sl[1] * __expf(sm[1] - M) +
                  sl[2] * __expf(sm[2] - M) + sl[3] * __expf(sm[3] - M);
  const float lz = M + logf(L);
#pragma unroll
  for (int i = 0; i < 31; ++i) {
    f32x4 v = *(const f32x4*)(p + (long)i * 1024 + t * 4);
    v[0] -= lz; v[1] -= lz; v[2] -= lz; v[3] -= lz;
    *(f32x4*)(p + (long)i * 1024 + t * 4) = v;
  }
  p[31744 + t] -= lz;
}

// ---------------------------------------------------------------------------
extern "C" void kernel_launch(void* const* d_in, const int* in_sizes, int n_in,
                              void* d_out, int out_size, void* d_ws,
                              size_t ws_size, hipStream_t stream) {
  (void)in_sizes; (void)n_in; (void)out_size; (void)ws_size;
  const int* src = (const int*)d_in[0];
  const int* tgt = (const int*)d_in[1];
  const int* src_mask = (const int*)d_in[2];
  const int* tgt_mask = (const int*)d_in[3];
  (void)tgt_mask;
  const float* src_emb = (const float*)d_in[4];
  const float* tgt_emb = (const float*)d_in[5];
  const float* in_f[40];
  for (int i = 0; i < 40; ++i) in_f[i] = (const float*)d_in[i];
  float* out = (float*)d_out;

  // ---- workspace carve-up ----
  char* wp = (char*)d_ws;
  auto alloc = [&](size_t bytes) -> char* {
    char* r = wp; wp += (bytes + 255) & ~(size_t)255; return r;
  };
  const long eQKV = (long)6 * 1536 * 512, eDD = (long)6 * 512 * 512,
             eDF = (long)6 * 2048 * 512;
  __bf16* encQKV = (__bf16*)alloc(eQKV * 2);
  __bf16* dsaQKV = (__bf16*)alloc(eQKV * 2);
  __bf16* dcaQKV = (__bf16*)alloc(eQKV * 2);
  __bf16* encWoT = (__bf16*)alloc(eDD * 2);
  __bf16* dsaWoT = (__bf16*)alloc(eDD * 2);
  __bf16* dcaWoT = (__bf16*)alloc(eDD * 2);
  __bf16* encW1T = (__bf16*)alloc(eDF * 2);
  __bf16* encW2T = (__bf16*)alloc(eDF * 2);
  __bf16* decW1T = (__bf16*)alloc(eDF * 2);
  __bf16* decW2T = (__bf16*)alloc(eDF * 2);
  __bf16* projT  = (__bf16*)alloc((long)32000 * 512 * 2);
  float*  x      = (float*)alloc((long)2048 * 512 * 4);
  __bf16* h      = (__bf16*)alloc((long)2048 * 512 * 2);
  __bf16* encb   = (__bf16*)alloc((long)2048 * 512 * 2);
  __bf16* qkv    = (__bf16*)alloc((long)2048 * 1536 * 2);
  __bf16* vT     = (__bf16*)alloc((long)16 * 64 * 1024 * 2);
  __bf16* ob     = (__bf16*)alloc((long)2048 * 512 * 2);
  __bf16* mid    = (__bf16*)alloc((long)2048 * 2048 * 2);

  auto tconv = [&](const float* in, __bf16* o, int R, int C, int Lz,
                   long outS, long outOff) {
    transpose_cvt<<<dim3(C / 32, R / 32, Lz), 256, 0, stream>>>(
        in, o, R, C, (long)R * C, outS, outOff);
  };
  // ---- weight conversion/transpose (per launch; ws is re-poisoned) ----
  tconv(in_f[6],  encQKV, 512, 512, 6, 1536 * 512, 0);
  tconv(in_f[8],  encQKV, 512, 512, 6, 1536 * 512, 512 * 512);
  tconv(in_f[10], encQKV, 512, 512, 6, 1536 * 512, 1024 * 512);
  tconv(in_f[12], encWoT, 512, 512, 6, 512 * 512, 0);
  tconv(in_f[14], encW1T, 512, 2048, 6, (long)2048 * 512, 0);
  tconv(in_f[16], encW2T, 2048, 512, 6, (long)2048 * 512, 0);
  tconv(in_f[18], dsaQKV, 512, 512, 6, 1536 * 512, 0);
  tconv(in_f[20], dsaQKV, 512, 512, 6, 1536 * 512, 512 * 512);
  tconv(in_f[22], dsaQKV, 512, 512, 6, 1536 * 512, 1024 * 512);
  tconv(in_f[24], dsaWoT, 512, 512, 6, 512 * 512, 0);
  tconv(in_f[26], dcaQKV, 512, 512, 6, 1536 * 512, 0);
  tconv(in_f[28], dcaQKV, 512, 512, 6, 1536 * 512, 512 * 512);
  tconv(in_f[30], dcaQKV, 512, 512, 6, 1536 * 512, 1024 * 512);
  tconv(in_f[32], dcaWoT, 512, 512, 6, 512 * 512, 0);
  tconv(in_f[34], decW1T, 512, 2048, 6, (long)2048 * 512, 0);
  tconv(in_f[36], decW2T, 2048, 512, 6, (long)2048 * 512, 0);
  tconv(in_f[38], projT, 512, 32000, 1, 0, 0);

  auto attn_core = [&](const int* mask, int mode, const __bf16* woT_l,
                       const float* bo_l) {
    vtrans_kernel<<<dim3(32, 2, 16), 256, 0, stream>>>(qkv, vT);
    if (mode == 0)
      flash_attn<0><<<dim3(16, 16), 256, 0, stream>>>(qkv, vT, mask, ob);
    else
      flash_attn<1><<<dim3(16, 16), 256, 0, stream>>>(qkv, vT, mask, ob);
    // x += O Wo + bo   (split-K 2, atomic)
    gemm_bt<64, 64, 4, false, false><<<dim3(8, 32, 2), 256, 0, stream>>>(
        ob, 512, 256, 0, woT_l, 512, 256, 0, x, 512, 0, 0, bo_l, nullptr,
        nullptr, 256, 1, 1.f);
  };

  auto ffn = [&](const __bf16* w1T_l, const float* b1_l, const __bf16* w2T_l,
                 const float* b2_l) {
    gemm_bt<128, 64, 1, false, false><<<dim3(32, 16, 1), 256, 0, stream>>>(
        h, 512, 0, 0, w1T_l, 512, 0, 0, mid, 2048, 0, 0, b1_l, nullptr,
        nullptr, 512, 1, 1.f);
    gemm_bt<64, 64, 4, false, false><<<dim3(8, 32, 2), 256, 0, stream>>>(
        mid, 2048, 1024, 0, w2T_l, 2048, 1024, 0, x, 512, 0, 0, b2_l, nullptr,
        nullptr, 1024, 1, 1.f);
  };

  const int rows = C_B * C_S;

  // ================= encoder =================
  embed_kernel<<<rows, 256, 0, stream>>>(src, src_emb, x);
  for (int i = 0; i < C_L; ++i) {
    const long oW = (long)i * 1536 * 512, oB = (long)i * 512;
    ln_kernel<<<rows, 256, 0, stream>>>(x, h);
    gemm_bt<128, 64, 0, true, false><<<dim3(24, 16, 1), 256, 0, stream>>>(
        h, 512, 0, 0, encQKV + oW, 512, 0, 0, qkv, 1536, 0, 0,
        in_f[7] + oB, in_f[9] + oB, in_f[11] + oB, 512, 1, 1.f);
    attn_core(src_mask, 0, encWoT + (long)i * 512 * 512, in_f[13] + oB);
    ln_kernel<<<rows, 256, 0, stream>>>(x, h);
    ffn(encW1T + (long)i * 2048 * 512, in_f[15] + (long)i * 2048,
        encW2T + (long)i * 2048 * 512, in_f[17] + oB);
  }
  ln_kernel<<<rows, 256, 0, stream>>>(x, encb);

  // ================= decoder =================
  embed_kernel<<<rows, 256, 0, stream>>>(tgt, tgt_emb, x);
  for (int i = 0; i < C_L; ++i) {
    const long oW = (long)i * 1536 * 512, oB = (long)i * 512;
    // self-attn (reference quirk: src_mask)
    ln_kernel<<<rows, 256, 0, stream>>>(x, h);
    gemm_bt<128, 64, 0, true, false><<<dim3(24, 16, 1), 256, 0, stream>>>(
        h, 512, 0, 0, dsaQKV + oW, 512, 0, 0, qkv, 1536, 0, 0,
        in_f[19] + oB, in_f[21] + oB, in_f[23] + oB, 512, 1, 1.f);
    attn_core(src_mask, 0, dsaWoT + (long)i * 512 * 512, in_f[25] + oB);
    // cross-attn (reference quirk: tgt_mask = causal); Q from h, K/V from encb
    ln_kernel<<<rows, 256, 0, stream>>>(x, h);
    gemm_bt<64, 64, 0, false, false><<<dim3(8, 32, 1), 256, 0, stream>>>(
        h, 512, 0, 0, dcaQKV + oW, 512, 0, 0, qkv, 1536, 0, 0,
        in_f[27] + oB, nullptr, nullptr, 512, 1, 1.f);
    gemm_bt<128, 64, 0, true, false><<<dim3(16, 16, 1), 256, 0, stream>>>(
        encb, 512, 0, 0, dcaQKV + oW + (long)512 * 512, 512, 0, 0, qkv + 512,
        1536, 0, 0, in_f[29] + oB, in_f[31] + oB, nullptr, 512, 1, 1.f);
    attn_core(nullptr, 1, dcaWoT + (long)i * 512 * 512, in_f[33] + oB);
    ln_kernel<<<rows, 256, 0, stream>>>(x, h);
    ffn(decW1T + (long)i * 2048 * 512, in_f[35] + (long)i * 2048,
        decW2T + (long)i * 2048 * 512, in_f[37] + oB);
  }
  ln_kernel<<<rows, 256, 0, stream>>>(x, h);

  // ---- final projection (SWAP grid: M-major for proj_w L2 reuse) ----
  gemm_bt<128, 128, 3, false, true><<<dim3(16, 250, 1), 256, 0, stream>>>(
      h, 512, 0, 0, projT, 512, 0, 0, out, 32000, 0, 0, in_f[39], nullptr,
      nullptr, 512, 1, 1.f);
  logsoftmax_kernel<<<rows, 256, 0, stream>>>(out);
}

// Round 3
// 2571.780 us; speedup vs baseline: 1.1174x; 1.1174x over previous
//
#include <hip/hip_runtime.h>
#include <math.h>

constexpr int C_B = 2, C_S = 1024, C_D = 512, C_H = 8, C_DH = 64,
              C_F = 2048, C_L = 6, C_V = 32000;
constexpr float C_EPS = 1e-6f;

using bf16x8 = __attribute__((ext_vector_type(8))) __bf16;
using bf16x4v = __attribute__((ext_vector_type(4))) __bf16;
using f32x4  = __attribute__((ext_vector_type(4))) float;

__device__ __forceinline__ f32x4 mfma16(bf16x8 a, bf16x8 b, f32x4 c) {
  return __builtin_amdgcn_mfma_f32_16x16x32_bf16(a, b, c, 0, 0, 0);
}

__device__ __forceinline__ void async16(const __bf16* g, __bf16* l) {
  __builtin_amdgcn_global_load_lds(
      (const __attribute__((address_space(1))) void*)g,
      (__attribute__((address_space(3))) void*)l, 16, 0, 0);
}

__device__ __forceinline__ float block_sum(float v, float* sbuf) {
#pragma unroll
  for (int o = 32; o > 0; o >>= 1) v += __shfl_down(v, o);
  __syncthreads();
  if ((threadIdx.x & 63) == 0) sbuf[threadIdx.x >> 6] = v;
  __syncthreads();
  return (sbuf[0] + sbuf[1]) + (sbuf[2] + sbuf[3]);
}

// ---------------------------------------------------------------------------
// bf16 GEMM, B in [N][K] layout. C[M,N] = scale*(A@B^T) + bias, epilogues:
// EPI 0: store bf16; 1: store bf16+relu; 3: store f32; 4: f32 atomicAdd
// (residual, bias only when zb==0; z = K-split index via sAb/sBb k-offsets).
// TRI: bias segmented per 512 cols (b0/b1/b2). SWAP: m from blockIdx.x.
// global_load_lds staging (16B/lane), XOR granule swizzle in LDS.
// ---------------------------------------------------------------------------
template <int BM, int BN, int EPI, bool TRI, bool SWAP>
__global__ __launch_bounds__(256) void gemm_bt(
    const __bf16* __restrict__ A, int lda, long sAb, long sAh,
    const __bf16* __restrict__ B, int ldb, long sBb, long sBh,
    void* __restrict__ Cv, int ldc, long sCb, long sCh,
    const float* __restrict__ b0, const float* __restrict__ b1,
    const float* __restrict__ b2, int K, int hdim, float scale) {
  constexpr int BK = 32;
  __shared__ __bf16 As[BM][BK];
  __shared__ __bf16 Bs[BN][BK];
  const int z = blockIdx.z;
  const int zb = z / hdim, zh = z - zb * hdim;
  const __bf16* Ap = A + (long)zb * sAb + (long)zh * sAh;
  const __bf16* Bp = B + (long)zb * sBb + (long)zh * sBh;
  const int m0 = (SWAP ? blockIdx.x : blockIdx.y) * BM;
  const int n0 = (SWAP ? blockIdx.y : blockIdx.x) * BN;
  const int t = threadIdx.x, lane = t & 63, w = t >> 6;
  const int wr = w >> 1, wc = w & 1;
  constexpr int WM = BM / 2, WN = BN / 2, TM = WM / 16, TN = WN / 16;
  constexpr int AI = BM / 64, BI = BN / 64;
  const int srow = lane >> 2;       // row within 16-row staging group
  const int sg = lane & 3;          // LDS granule this lane fills
  const int fr = lane & 15, fq = lane >> 4;

  f32x4 acc[TM][TN] = {};
  for (int k0 = 0; k0 < K; k0 += BK) {
#pragma unroll
    for (int j = 0; j < AI; ++j) {
      const int r0 = w * (AI * 16) + j * 16;
      const int row = r0 + srow;
      const int s = sg ^ ((row >> 1) & 3);  // global k-seg for this granule
      async16(Ap + (long)(m0 + row) * lda + (k0 + s * 8), &As[r0][0]);
    }
#pragma unroll
    for (int j = 0; j < BI; ++j) {
      const int r0 = w * (BI * 16) + j * 16;
      const int row = r0 + srow;
      const int s = sg ^ ((row >> 1) & 3);
      async16(Bp + (long)(n0 + row) * ldb + (k0 + s * 8), &Bs[r0][0]);
    }
    __syncthreads();
    bf16x8 af[TM], bfr[TN];
#pragma unroll
    for (int i = 0; i < TM; ++i) {
      const int row = wr * WM + i * 16 + fr;
      const int g = fq ^ ((row >> 1) & 3);
      af[i] = *(const bf16x8*)&As[row][g * 8];
    }
#pragma unroll
    for (int i = 0; i < TN; ++i) {
      const int row = wc * WN + i * 16 + fr;
      const int g = fq ^ ((row >> 1) & 3);
      bfr[i] = *(const bf16x8*)&Bs[row][g * 8];
    }
#pragma unroll
    for (int i = 0; i < TM; ++i)
#pragma unroll
      for (int j = 0; j < TN; ++j) acc[i][j] = mfma16(af[i], bfr[j], acc[i][j]);
    __syncthreads();
  }

  const long co = (long)zb * sCb + (long)zh * sCh;
  const int rq = (lane >> 4) * 4;
#pragma unroll
  for (int i = 0; i < TM; ++i) {
#pragma unroll
    for (int j = 0; j < TN; ++j) {
      const int colg = n0 + wc * WN + j * 16 + fr;
      float bv = 0.f;
      if (b0) {
        if (TRI) {
          const float* bp = colg < 512 ? b0 : (colg < 1024 ? b1 : b2);
          bv = bp[colg & 511];
        } else {
          bv = b0[colg];
        }
      }
      if (EPI == 4 && zb != 0) bv = 0.f;
#pragma unroll
      for (int r = 0; r < 4; ++r) {
        const int rowg = m0 + wr * WM + i * 16 + rq + r;
        const long ci = co + (long)rowg * ldc + colg;
        float v = acc[i][j][r] * scale + bv;
        if (EPI == 0) ((__bf16*)Cv)[ci] = (__bf16)v;
        else if (EPI == 1) ((__bf16*)Cv)[ci] = (__bf16)fmaxf(v, 0.f);
        else if (EPI == 3) ((float*)Cv)[ci] = v;
        else atomicAdd((float*)Cv + ci, v);
      }
    }
  }
}

// ---------------------------------------------------------------------------
// Fused flash attention, KV-split. qkv[b*S+s][1536] (Q|K|V, h*64+dh within
// each 512), vT[(b*8+h)][dh][s]. Output ob[b*S+s][h*64+dh] bf16.
// Grid: x = 16-row q-tile (64 tiles), y = b*8+h -> 1024 blocks (4 blocks/CU,
// 4 waves/SIMD). Each of the 4 waves processes interleaved KV tiles
// (kt = w, w+4, ...) with private online-softmax state (m,l,O); partials are
// merged exactly via LDS: O = sum_w exp(m_w-M) O_w / sum_w exp(m_w-M) l_w.
// Per-wave P tile aliases the low 2KB of its f32 merge quadrant (barrier
// separates the two uses). K/V read direct from global (L2-resident).
// MODE 0: key mask from src_mask[b][k]. MODE 1: analytic causal (tril).
// ---------------------------------------------------------------------------
template <int MODE>
__global__ __launch_bounds__(256) void flash_attn(
    const __bf16* __restrict__ qkv, const __bf16* __restrict__ vT,
    const int* __restrict__ mask, __bf16* __restrict__ ob) {
  __shared__ float Ob[4][16][64];       // per-wave partial O (f32)
  __shared__ float Mw[4][16], Lw[4][16];
  const int z = blockIdx.y, b = z >> 3, h = z & 7;
  const int qt = blockIdx.x, q0 = qt * 16;
  const int t = threadIdx.x, lane = t & 63, w = t >> 6;
  const int fr = lane & 15, fq = lane >> 4;

  // Q fragments (row = fr, k-dim granule = fq*8, 2 chunks of 32 over D=64);
  // all 4 waves load the same 16 rows (L1 broadcast).
  const __bf16* qbase = qkv + ((long)(b << 10) + q0 + fr) * 1536 + h * 64;
  const bf16x8 qf0 = *(const bf16x8*)(qbase + fq * 8);
  const bf16x8 qf1 = *(const bf16x8*)(qbase + 32 + fq * 8);
  const __bf16* kbase = qkv + (long)(b << 10) * 1536 + 512 + h * 64;
  const __bf16* vbase = vT + (long)z * 64 * 1024;

  f32x4 oacc[4] = {};
  float m[4], l[4];
#pragma unroll
  for (int r = 0; r < 4; ++r) { m[r] = -3e38f; l[r] = 0.f; }
  const int myq = q0 + fq * 4;  // C-layout row base for this lane

  __bf16* pw = (__bf16*)&Ob[w][0][0];  // wave-private P tile (alias)
  const int nkv = (MODE == 1) ? (qt >> 2) + 1 : 16;
  for (int kt = w; kt < nkv; kt += 4) {
    const int k0 = kt * 64;
    // ---- S = Q K^T ----
    f32x4 sc[4] = {};
#pragma unroll
    for (int j = 0; j < 4; ++j) {
      const __bf16* kp = kbase + (long)(k0 + j * 16 + fr) * 1536;
      const bf16x8 kf0 = *(const bf16x8*)(kp + fq * 8);
      const bf16x8 kf1 = *(const bf16x8*)(kp + 32 + fq * 8);
      sc[j] = mfma16(qf0, kf0, sc[j]);
      sc[j] = mfma16(qf1, kf1, sc[j]);
    }
    // ---- mask + scale ----
    float sv[4][4];
    if (MODE == 0) {
#pragma unroll
      for (int j = 0; j < 4; ++j) {
        const int km = mask[(b << 10) + k0 + j * 16 + fr];
#pragma unroll
        for (int r = 0; r < 4; ++r)
          sv[j][r] = km != 0 ? sc[j][r] * 0.125f : -1e9f;
      }
    } else {
#pragma unroll
      for (int j = 0; j < 4; ++j) {
        const int kpos = k0 + j * 16 + fr;
#pragma unroll
        for (int r = 0; r < 4; ++r)
          sv[j][r] = kpos <= myq + r ? sc[j][r] * 0.125f : -1e9f;
      }
    }
    // ---- online softmax (rows live across the 16-lane fr dimension) ----
    float p[4][4];
#pragma unroll
    for (int r = 0; r < 4; ++r) {
      float tm = fmaxf(fmaxf(sv[0][r], sv[1][r]), fmaxf(sv[2][r], sv[3][r]));
#pragma unroll
      for (int o = 8; o > 0; o >>= 1) tm = fmaxf(tm, __shfl_xor(tm, o));
      const float mn = fmaxf(m[r], tm);
      const float corr = __expf(m[r] - mn);
      m[r] = mn;
      float rs = 0.f;
#pragma unroll
      for (int j = 0; j < 4; ++j) { p[j][r] = __expf(sv[j][r] - mn); rs += p[j][r]; }
#pragma unroll
      for (int o = 8; o > 0; o >>= 1) rs += __shfl_xor(rs, o);
      l[r] = l[r] * corr + rs;
#pragma unroll
      for (int j = 0; j < 4; ++j) oacc[j][r] *= corr;
    }
    // ---- P -> LDS (granule XOR swizzle, wave-private: no barrier) ----
#pragma unroll
    for (int j = 0; j < 4; ++j) {
      const int c = j >> 1;
      const int gc = (2 * j + (fr >> 3)) & 3;
      const int e = fr & 7;
#pragma unroll
      for (int r = 0; r < 4; ++r) {
        const int row = fq * 4 + r;
        const int slot = c * 4 + (gc ^ ((row >> 1) & 3));
        pw[row * 64 + slot * 8 + e] = (__bf16)p[j][r];
      }
    }
    // ---- O += P V ----
#pragma unroll
    for (int c = 0; c < 2; ++c) {
      const int slot = c * 4 + (fq ^ ((fr >> 1) & 3));
      const bf16x8 pa = *(const bf16x8*)(pw + fr * 64 + slot * 8);
#pragma unroll
      for (int j = 0; j < 4; ++j) {
        const bf16x8 vf = *(const bf16x8*)(vbase + (long)(j * 16 + fr) * 1024 +
                                           k0 + c * 32 + fq * 8);
        oacc[j] = mfma16(pa, vf, oacc[j]);
      }
    }
  }
  __syncthreads();  // all P reads done before Ob f32 overwrite
  // ---- write per-wave partials ----
#pragma unroll
  for (int j = 0; j < 4; ++j)
#pragma unroll
    for (int r = 0; r < 4; ++r) Ob[w][fq * 4 + r][j * 16 + fr] = oacc[j][r];
  if (fr == 0) {
#pragma unroll
    for (int r = 0; r < 4; ++r) { Mw[w][fq * 4 + r] = m[r]; Lw[w][fq * 4 + r] = l[r]; }
  }
  __syncthreads();
  // ---- exact merge of the 4 wave partials; thread t -> row t>>4, 4 cols ----
  const int q = t >> 4, c0 = (t & 15) * 4;
  const float M = fmaxf(fmaxf(Mw[0][q], Mw[1][q]), fmaxf(Mw[2][q], Mw[3][q]));
  const float cf0 = __expf(Mw[0][q] - M), cf1 = __expf(Mw[1][q] - M),
              cf2 = __expf(Mw[2][q] - M), cf3 = __expf(Mw[3][q] - M);
  const float L = cf0 * Lw[0][q] + cf1 * Lw[1][q] +
                  cf2 * Lw[2][q] + cf3 * Lw[3][q];
  const float invL = 1.0f / L;
  __bf16* op = ob + ((long)(b << 10) + q0 + q) * 512 + h * 64 + c0;
#pragma unroll
  for (int cc = 0; cc < 4; ++cc) {
    const float v = cf0 * Ob[0][q][c0 + cc] + cf1 * Ob[1][q][c0 + cc] +
                    cf2 * Ob[2][q][c0 + cc] + cf3 * Ob[3][q][c0 + cc];
    op[cc] = (__bf16)(v * invL);
  }
}

// ---------------------------------------------------------------------------
// transpose + f32->bf16: in [z][R][C] f32 -> out [z][C][R] bf16 (+outOff)
// ---------------------------------------------------------------------------
__global__ __launch_bounds__(256) void transpose_cvt(
    const float* __restrict__ in, __bf16* __restrict__ out, int R, int C,
    long inS, long outS, long outOff) {
  __shared__ __bf16 tile[32][33];
  in += (long)blockIdx.z * inS;
  out += (long)blockIdx.z * outS + outOff;
  const int c0 = blockIdx.x * 32, r0 = blockIdx.y * 32;
  const int tc = threadIdx.x & 31, tr = threadIdx.x >> 5;  // 8 rows/pass
#pragma unroll
  for (int j = 0; j < 32; j += 8)
    tile[tr + j][tc] = (__bf16)in[(long)(r0 + tr + j) * C + (c0 + tc)];
  __syncthreads();
#pragma unroll
  for (int j = 0; j < 32; j += 8)
    out[(long)(c0 + tr + j) * R + (r0 + tc)] = tile[tc][tr + j];
}

// ---------------------------------------------------------------------------
// V transpose: qkv[b*S+s][1024 + h*64 + dh] -> vT[(b*8+h)*64 + dh][s]
// ---------------------------------------------------------------------------
__global__ __launch_bounds__(256) void vtrans_kernel(
    const __bf16* __restrict__ qkv, __bf16* __restrict__ vT) {
  __shared__ __bf16 tile[32][33];
  const int z = blockIdx.z, b = z >> 3, h = z & 7;
  const int s0 = blockIdx.x * 32, d0 = blockIdx.y * 32;
  const int tc = threadIdx.x & 31, tr = threadIdx.x >> 5;
  const __bf16* src = qkv + (long)(b << 10) * 1536 + 1024 + h * 64;
#pragma unroll
  for (int j = 0; j < 32; j += 8)
    tile[tr + j][tc] = src[(long)(s0 + tr + j) * 1536 + (d0 + tc)];
  __syncthreads();
  __bf16* dst = vT + (long)z * 64 * 1024;
#pragma unroll
  for (int j = 0; j < 32; j += 8)
    dst[(long)(d0 + tr + j) * 1024 + (s0 + tc)] = tile[tc][tr + j];
}

// ---------------------------------------------------------------------------
__global__ __launch_bounds__(256) void embed_kernel(
    const int* __restrict__ tok, const float* __restrict__ emb,
    float* __restrict__ out) {
  const int bs = blockIdx.x;
  const int spos = bs & (C_S - 1);
  const int tk = tok[bs];
  const float* ep = emb + (long)tk * C_D;
  float* op = out + (long)bs * C_D;
  for (int d = threadIdx.x; d < C_D; d += 256) {
    const int i2 = d & ~1;
    const float freq = __expf((float)i2 * (-9.210340371976184f / 512.0f));
    const float ang = (float)spos * freq;
    const float pe = (d & 1) ? cosf(ang) : sinf(ang);
    op[d] = ep[d] * 22.62741699796952f + pe;
  }
}

__global__ __launch_bounds__(256) void ln_kernel(const float* __restrict__ x,
                                                 __bf16* __restrict__ out) {
  __shared__ float sbuf[4];
  const long row = blockIdx.x;
  const float* xp = x + row * C_D;
  __bf16* op = out + row * C_D;
  const int t = threadIdx.x;
  const float v0 = xp[t];
  const float v1 = xp[t + 256];
  const float mean = block_sum(v0 + v1, sbuf) * (1.0f / 512.0f);
  const float d0 = v0 - mean, d1 = v1 - mean;
  const float ss = block_sum(d0 * d0 + d1 * d1, sbuf);
  const float stdv = sqrtf(ss * (1.0f / 511.0f));
  const float inv = 1.0f / (stdv + C_EPS);
  op[t] = (__bf16)(d0 * inv);
  op[t + 256] = (__bf16)(d1 * inv);
}

// ---------------------------------------------------------------------------
// log_softmax over rows of V=32000 f32, in-place.
// float4 loads (16B/lane), dual online (m,l) states to break the serial
// exp-dependence chain, fully unrolled so loads batch under one vmcnt window.
// Row = 31 float4 iters (31744 elems) + 256-elem scalar tail.
// ---------------------------------------------------------------------------
__global__ __launch_bounds__(256) void logsoftmax_kernel(float* __restrict__ out) {
  __shared__ float sm[4], sl[4];
  const long row = blockIdx.x;
  float* p = out + row * C_V;
  const int t = threadIdx.x, lane = t & 63, w = t >> 6;
  float m0 = -1e30f, l0 = 0.f, m1 = -1e30f, l1 = 0.f;
#pragma unroll
  for (int i = 0; i < 30; i += 2) {
    const f32x4 a = *(const f32x4*)(p + (long)i * 1024 + t * 4);
    const f32x4 b = *(const f32x4*)(p + (long)(i + 1) * 1024 + t * 4);
    {
      const float mx = fmaxf(fmaxf(a[0], a[1]), fmaxf(a[2], a[3]));
      const float mn = fmaxf(m0, mx);
      l0 = l0 * __expf(m0 - mn) +
           ((__expf(a[0] - mn) + __expf(a[1] - mn)) +
            (__expf(a[2] - mn) + __expf(a[3] - mn)));
      m0 = mn;
    }
    {
      const float mx = fmaxf(fmaxf(b[0], b[1]), fmaxf(b[2], b[3]));
      const float mn = fmaxf(m1, mx);
      l1 = l1 * __expf(m1 - mn) +
           ((__expf(b[0] - mn) + __expf(b[1] - mn)) +
            (__expf(b[2] - mn) + __expf(b[3] - mn)));
      m1 = mn;
    }
  }
  {  // vector iter 30
    const f32x4 a = *(const f32x4*)(p + (long)30 * 1024 + t * 4);
    const float mx = fmaxf(fmaxf(a[0], a[1]), fmaxf(a[2], a[3]));
    const float mn = fmaxf(m0, mx);
    l0 = l0 * __expf(m0 - mn) +
         ((__expf(a[0] - mn) + __expf(a[1] - mn)) +
          (__expf(a[2] - mn) + __expf(a[3] - mn)));
    m0 = mn;
  }
  {  // scalar tail: elements 31744..31999
    const float v = p[31744 + t];
    const float mn = fmaxf(m1, v);
    l1 = l1 * __expf(m1 - mn) + __expf(v - mn);
    m1 = mn;
  }
  // merge dual states
  float m = fmaxf(m0, m1);
  float l = l0 * __expf(m0 - m) + l1 * __expf(m1 - m);
#pragma unroll
  for (int o = 32; o > 0; o >>= 1) {
    const float m2 = __shfl_down(m, o), l2 = __shfl_down(l, o);
    const float M = fmaxf(m, m2);
    l = l * __expf(m - M) + l2 * __expf(m2 - M);
    m = M;
  }
  if (lane == 0) { sm[w] = m; sl[w] = l; }
  __syncthreads();
  const float M = fmaxf(fmaxf(sm[0], sm[1]), fmaxf(sm[2], sm[3]));
  const float L = sl[0] * __expf(sm[0] - M) + sl[1] * __expf(sm[1] - M) +
                  sl[2] * __expf(sm[2] - M) + sl[3] * __expf(sm[3] - M);
  const float lz = M + logf(L);
#pragma unroll
  for (int i = 0; i < 31; ++i) {
    f32x4 v = *(const f32x4*)(p + (long)i * 1024 + t * 4);
    v[0] -= lz; v[1] -= lz; v[2] -= lz; v[3] -= lz;
    *(f32x4*)(p + (long)i * 1024 + t * 4) = v;
  }
  p[31744 + t] -= lz;
}

// ---------------------------------------------------------------------------
extern "C" void kernel_launch(void* const* d_in, const int* in_sizes, int n_in,
                              void* d_out, int out_size, void* d_ws,
                              size_t ws_size, hipStream_t stream) {
  (void)in_sizes; (void)n_in; (void)out_size; (void)ws_size;
  const int* src = (const int*)d_in[0];
  const int* tgt = (const int*)d_in[1];
  const int* src_mask = (const int*)d_in[2];
  const int* tgt_mask = (const int*)d_in[3];
  (void)tgt_mask;
  const float* src_emb = (const float*)d_in[4];
  const float* tgt_emb = (const float*)d_in[5];
  const float* in_f[40];
  for (int i = 0; i < 40; ++i) in_f[i] = (const float*)d_in[i];
  float* out = (float*)d_out;

  // ---- workspace carve-up ----
  char* wp = (char*)d_ws;
  auto alloc = [&](size_t bytes) -> char* {
    char* r = wp; wp += (bytes + 255) & ~(size_t)255; return r;
  };
  const long eQKV = (long)6 * 1536 * 512, eDD = (long)6 * 512 * 512,
             eDF = (long)6 * 2048 * 512;
  __bf16* encQKV = (__bf16*)alloc(eQKV * 2);
  __bf16* dsaQKV = (__bf16*)alloc(eQKV * 2);
  __bf16* dcaQKV = (__bf16*)alloc(eQKV * 2);
  __bf16* encWoT = (__bf16*)alloc(eDD * 2);
  __bf16* dsaWoT = (__bf16*)alloc(eDD * 2);
  __bf16* dcaWoT = (__bf16*)alloc(eDD * 2);
  __bf16* encW1T = (__bf16*)alloc(eDF * 2);
  __bf16* encW2T = (__bf16*)alloc(eDF * 2);
  __bf16* decW1T = (__bf16*)alloc(eDF * 2);
  __bf16* decW2T = (__bf16*)alloc(eDF * 2);
  __bf16* projT  = (__bf16*)alloc((long)32000 * 512 * 2);
  float*  x      = (float*)alloc((long)2048 * 512 * 4);
  __bf16* h      = (__bf16*)alloc((long)2048 * 512 * 2);
  __bf16* encb   = (__bf16*)alloc((long)2048 * 512 * 2);
  __bf16* qkv    = (__bf16*)alloc((long)2048 * 1536 * 2);
  __bf16* vT     = (__bf16*)alloc((long)16 * 64 * 1024 * 2);
  __bf16* ob     = (__bf16*)alloc((long)2048 * 512 * 2);
  __bf16* mid    = (__bf16*)alloc((long)2048 * 2048 * 2);

  auto tconv = [&](const float* in, __bf16* o, int R, int C, int Lz,
                   long outS, long outOff) {
    transpose_cvt<<<dim3(C / 32, R / 32, Lz), 256, 0, stream>>>(
        in, o, R, C, (long)R * C, outS, outOff);
  };
  // ---- weight conversion/transpose (per launch; ws is re-poisoned) ----
  tconv(in_f[6],  encQKV, 512, 512, 6, 1536 * 512, 0);
  tconv(in_f[8],  encQKV, 512, 512, 6, 1536 * 512, 512 * 512);
  tconv(in_f[10], encQKV, 512, 512, 6, 1536 * 512, 1024 * 512);
  tconv(in_f[12], encWoT, 512, 512, 6, 512 * 512, 0);
  tconv(in_f[14], encW1T, 512, 2048, 6, (long)2048 * 512, 0);
  tconv(in_f[16], encW2T, 2048, 512, 6, (long)2048 * 512, 0);
  tconv(in_f[18], dsaQKV, 512, 512, 6, 1536 * 512, 0);
  tconv(in_f[20], dsaQKV, 512, 512, 6, 1536 * 512, 512 * 512);
  tconv(in_f[22], dsaQKV, 512, 512, 6, 1536 * 512, 1024 * 512);
  tconv(in_f[24], dsaWoT, 512, 512, 6, 512 * 512, 0);
  tconv(in_f[26], dcaQKV, 512, 512, 6, 1536 * 512, 0);
  tconv(in_f[28], dcaQKV, 512, 512, 6, 1536 * 512, 512 * 512);
  tconv(in_f[30], dcaQKV, 512, 512, 6, 1536 * 512, 1024 * 512);
  tconv(in_f[32], dcaWoT, 512, 512, 6, 512 * 512, 0);
  tconv(in_f[34], decW1T, 512, 2048, 6, (long)2048 * 512, 0);
  tconv(in_f[36], decW2T, 2048, 512, 6, (long)2048 * 512, 0);
  tconv(in_f[38], projT, 512, 32000, 1, 0, 0);

  auto attn_core = [&](const int* mask, int mode, const __bf16* woT_l,
                       const float* bo_l) {
    vtrans_kernel<<<dim3(32, 2, 16), 256, 0, stream>>>(qkv, vT);
    if (mode == 0)
      flash_attn<0><<<dim3(64, 16), 256, 0, stream>>>(qkv, vT, mask, ob);
    else
      flash_attn<1><<<dim3(64, 16), 256, 0, stream>>>(qkv, vT, mask, ob);
    // x += O Wo + bo   (split-K 2, atomic)
    gemm_bt<64, 64, 4, false, false><<<dim3(8, 32, 2), 256, 0, stream>>>(
        ob, 512, 256, 0, woT_l, 512, 256, 0, x, 512, 0, 0, bo_l, nullptr,
        nullptr, 256, 1, 1.f);
  };

  auto ffn = [&](const __bf16* w1T_l, const float* b1_l, const __bf16* w2T_l,
                 const float* b2_l) {
    gemm_bt<128, 64, 1, false, false><<<dim3(32, 16, 1), 256, 0, stream>>>(
        h, 512, 0, 0, w1T_l, 512, 0, 0, mid, 2048, 0, 0, b1_l, nullptr,
        nullptr, 512, 1, 1.f);
    gemm_bt<64, 64, 4, false, false><<<dim3(8, 32, 2), 256, 0, stream>>>(
        mid, 2048, 1024, 0, w2T_l, 2048, 1024, 0, x, 512, 0, 0, b2_l, nullptr,
        nullptr, 1024, 1, 1.f);
  };

  const int rows = C_B * C_S;

  // ================= encoder =================
  embed_kernel<<<rows, 256, 0, stream>>>(src, src_emb, x);
  for (int i = 0; i < C_L; ++i) {
    const long oW = (long)i * 1536 * 512, oB = (long)i * 512;
    ln_kernel<<<rows, 256, 0, stream>>>(x, h);
    gemm_bt<128, 64, 0, true, false><<<dim3(24, 16, 1), 256, 0, stream>>>(
        h, 512, 0, 0, encQKV + oW, 512, 0, 0, qkv, 1536, 0, 0,
        in_f[7] + oB, in_f[9] + oB, in_f[11] + oB, 512, 1, 1.f);
    attn_core(src_mask, 0, encWoT + (long)i * 512 * 512, in_f[13] + oB);
    ln_kernel<<<rows, 256, 0, stream>>>(x, h);
    ffn(encW1T + (long)i * 2048 * 512, in_f[15] + (long)i * 2048,
        encW2T + (long)i * 2048 * 512, in_f[17] + oB);
  }
  ln_kernel<<<rows, 256, 0, stream>>>(x, encb);

  // ================= decoder =================
  embed_kernel<<<rows, 256, 0, stream>>>(tgt, tgt_emb, x);
  for (int i = 0; i < C_L; ++i) {
    const long oW = (long)i * 1536 * 512, oB = (long)i * 512;
    // self-attn (reference quirk: src_mask)
    ln_kernel<<<rows, 256, 0, stream>>>(x, h);
    gemm_bt<128, 64, 0, true, false><<<dim3(24, 16, 1), 256, 0, stream>>>(
        h, 512, 0, 0, dsaQKV + oW, 512, 0, 0, qkv, 1536, 0, 0,
        in_f[19] + oB, in_f[21] + oB, in_f[23] + oB, 512, 1, 1.f);
    attn_core(src_mask, 0, dsaWoT + (long)i * 512 * 512, in_f[25] + oB);
    // cross-attn (reference quirk: tgt_mask = causal); Q from h, K/V from encb
    ln_kernel<<<rows, 256, 0, stream>>>(x, h);
    gemm_bt<64, 64, 0, false, false><<<dim3(8, 32, 1), 256, 0, stream>>>(
        h, 512, 0, 0, dcaQKV + oW, 512, 0, 0, qkv, 1536, 0, 0,
        in_f[27] + oB, nullptr, nullptr, 512, 1, 1.f);
    gemm_bt<128, 64, 0, true, false><<<dim3(16, 16, 1), 256, 0, stream>>>(
        encb, 512, 0, 0, dcaQKV + oW + (long)512 * 512, 512, 0, 0, qkv + 512,
        1536, 0, 0, in_f[29] + oB, in_f[31] + oB, nullptr, 512, 1, 1.f);
    attn_core(nullptr, 1, dcaWoT + (long)i * 512 * 512, in_f[33] + oB);
    ln_kernel<<<rows, 256, 0, stream>>>(x, h);
    ffn(decW1T + (long)i * 2048 * 512, in_f[35] + (long)i * 2048,
        decW2T + (long)i * 2048 * 512, in_f[37] + oB);
  }
  ln_kernel<<<rows, 256, 0, stream>>>(x, h);

  // ---- final projection (SWAP grid: M-major for proj_w L2 reuse) ----
  gemm_bt<128, 128, 3, false, true><<<dim3(16, 250, 1), 256, 0, stream>>>(
      h, 512, 0, 0, projT, 512, 0, 0, out, 32000, 0, 0, in_f[39], nullptr,
      nullptr, 512, 1, 1.f);
  logsoftmax_kernel<<<rows, 256, 0, stream>>>(out);
}

// Round 4
// 2502.546 us; speedup vs baseline: 1.1483x; 1.0277x over previous
//
#include <hip/hip_runtime.h>
#include <math.h>

constexpr int C_B = 2, C_S = 1024, C_D = 512, C_H = 8, C_DH = 64,
              C_F = 2048, C_L = 6, C_V = 32000;
constexpr float C_EPS = 1e-6f;

using bf16x8 = __attribute__((ext_vector_type(8))) __bf16;
using bf16x4v = __attribute__((ext_vector_type(4))) __bf16;
using f32x4  = __attribute__((ext_vector_type(4))) float;

__device__ __forceinline__ f32x4 mfma16(bf16x8 a, bf16x8 b, f32x4 c) {
  return __builtin_amdgcn_mfma_f32_16x16x32_bf16(a, b, c, 0, 0, 0);
}

__device__ __forceinline__ void async16(const __bf16* g, __bf16* l) {
  __builtin_amdgcn_global_load_lds(
      (const __attribute__((address_space(1))) void*)g,
      (__attribute__((address_space(3))) void*)l, 16, 0, 0);
}

__device__ __forceinline__ float block_sum(float v, float* sbuf) {
#pragma unroll
  for (int o = 32; o > 0; o >>= 1) v += __shfl_down(v, o);
  __syncthreads();
  if ((threadIdx.x & 63) == 0) sbuf[threadIdx.x >> 6] = v;
  __syncthreads();
  return (sbuf[0] + sbuf[1]) + (sbuf[2] + sbuf[3]);
}

// ---------------------------------------------------------------------------
// bf16 GEMM, B in [N][K] layout. C[M,N] = scale*(A@B^T) + bias, epilogues:
// EPI 0: store bf16; 1: store bf16+relu; 3: store f32; 4: f32 atomicAdd
// (residual, bias only when zb==0; z = K-split index via sAb/sBb k-offsets).
// TRI: bias segmented per 512 cols (b0/b1/b2). SWAP: m from blockIdx.x.
// global_load_lds staging (16B/lane), XOR granule swizzle in LDS.
// 2-phase double-buffered pipeline (T3-min): STAGE(next) issued before
// compute(cur); single barrier per K-iter whose compiler-emitted vmcnt(0)
// drain overlaps the next-tile loads with this tile's MFMAs. This matters
// because several call sites run at only 1-2 blocks/CU (no wave-level
// overlap to hide the staging latency).
// ---------------------------------------------------------------------------
template <int BM, int BN, int EPI, bool TRI, bool SWAP>
__global__ __launch_bounds__(256) void gemm_bt(
    const __bf16* __restrict__ A, int lda, long sAb, long sAh,
    const __bf16* __restrict__ B, int ldb, long sBb, long sBh,
    void* __restrict__ Cv, int ldc, long sCb, long sCh,
    const float* __restrict__ b0, const float* __restrict__ b1,
    const float* __restrict__ b2, int K, int hdim, float scale) {
  constexpr int BK = 32;
  __shared__ __bf16 As[2][BM][BK];
  __shared__ __bf16 Bs[2][BN][BK];
  const int z = blockIdx.z;
  const int zb = z / hdim, zh = z - zb * hdim;
  const __bf16* Ap = A + (long)zb * sAb + (long)zh * sAh;
  const __bf16* Bp = B + (long)zb * sBb + (long)zh * sBh;
  const int m0 = (SWAP ? blockIdx.x : blockIdx.y) * BM;
  const int n0 = (SWAP ? blockIdx.y : blockIdx.x) * BN;
  const int t = threadIdx.x, lane = t & 63, w = t >> 6;
  const int wr = w >> 1, wc = w & 1;
  constexpr int WM = BM / 2, WN = BN / 2, TM = WM / 16, TN = WN / 16;
  constexpr int AI = BM / 64, BI = BN / 64;
  const int srow = lane >> 2;       // row within 16-row staging group
  const int sg = lane & 3;          // LDS granule this lane fills
  const int fr = lane & 15, fq = lane >> 4;

  auto stage = [&](int buf, int k0) {
#pragma unroll
    for (int j = 0; j < AI; ++j) {
      const int r0 = w * (AI * 16) + j * 16;
      const int row = r0 + srow;
      const int s = sg ^ ((row >> 1) & 3);  // global k-seg for this granule
      async16(Ap + (long)(m0 + row) * lda + (k0 + s * 8), &As[buf][r0][0]);
    }
#pragma unroll
    for (int j = 0; j < BI; ++j) {
      const int r0 = w * (BI * 16) + j * 16;
      const int row = r0 + srow;
      const int s = sg ^ ((row >> 1) & 3);
      async16(Bp + (long)(n0 + row) * ldb + (k0 + s * 8), &Bs[buf][r0][0]);
    }
  };

  f32x4 acc[TM][TN] = {};
  const int nt = K / BK;
  stage(0, 0);
  __syncthreads();  // compiler drains vmcnt(0) before s_barrier
  int cur = 0;
  for (int ti = 0; ti < nt; ++ti) {
    if (ti + 1 < nt) stage(cur ^ 1, (ti + 1) * BK);  // fly during MFMAs
    bf16x8 af[TM], bfr[TN];
#pragma unroll
    for (int i = 0; i < TM; ++i) {
      const int row = wr * WM + i * 16 + fr;
      const int g = fq ^ ((row >> 1) & 3);
      af[i] = *(const bf16x8*)&As[cur][row][g * 8];
    }
#pragma unroll
    for (int i = 0; i < TN; ++i) {
      const int row = wc * WN + i * 16 + fr;
      const int g = fq ^ ((row >> 1) & 3);
      bfr[i] = *(const bf16x8*)&Bs[cur][row][g * 8];
    }
#pragma unroll
    for (int i = 0; i < TM; ++i)
#pragma unroll
      for (int j = 0; j < TN; ++j) acc[i][j] = mfma16(af[i], bfr[j], acc[i][j]);
    __syncthreads();  // drains next-tile loads (overlapped) + syncs reuse
    cur ^= 1;
  }

  const long co = (long)zb * sCb + (long)zh * sCh;
  const int rq = (lane >> 4) * 4;
#pragma unroll
  for (int i = 0; i < TM; ++i) {
#pragma unroll
    for (int j = 0; j < TN; ++j) {
      const int colg = n0 + wc * WN + j * 16 + fr;
      float bv = 0.f;
      if (b0) {
        if (TRI) {
          const float* bp = colg < 512 ? b0 : (colg < 1024 ? b1 : b2);
          bv = bp[colg & 511];
        } else {
          bv = b0[colg];
        }
      }
      if (EPI == 4 && zb != 0) bv = 0.f;
#pragma unroll
      for (int r = 0; r < 4; ++r) {
        const int rowg = m0 + wr * WM + i * 16 + rq + r;
        const long ci = co + (long)rowg * ldc + colg;
        float v = acc[i][j][r] * scale + bv;
        if (EPI == 0) ((__bf16*)Cv)[ci] = (__bf16)v;
        else if (EPI == 1) ((__bf16*)Cv)[ci] = (__bf16)fmaxf(v, 0.f);
        else if (EPI == 3) ((float*)Cv)[ci] = v;
        else atomicAdd((float*)Cv + ci, v);
      }
    }
  }
}

// ---------------------------------------------------------------------------
// Fused flash attention, KV-split. qkv[b*S+s][1536] (Q|K|V, h*64+dh within
// each 512), vT[(b*8+h)][dh][s]. Output ob[b*S+s][h*64+dh] bf16.
// Grid: x = 16-row q-tile (64 tiles), y = b*8+h -> 1024 blocks (4 blocks/CU,
// 4 waves/SIMD). Each of the 4 waves processes interleaved KV tiles
// (kt = w, w+4, ...) with private online-softmax state (m,l,O); partials are
// merged exactly via LDS: O = sum_w exp(m_w-M) O_w / sum_w exp(m_w-M) l_w.
// Per-wave P tile aliases the low 2KB of its f32 merge quadrant (barrier
// separates the two uses). K/V read direct from global (L2-resident).
// MODE 0: key mask from src_mask[b][k]. MODE 1: analytic causal (tril).
// ---------------------------------------------------------------------------
template <int MODE>
__global__ __launch_bounds__(256) void flash_attn(
    const __bf16* __restrict__ qkv, const __bf16* __restrict__ vT,
    const int* __restrict__ mask, __bf16* __restrict__ ob) {
  __shared__ float Ob[4][16][64];       // per-wave partial O (f32)
  __shared__ float Mw[4][16], Lw[4][16];
  const int z = blockIdx.y, b = z >> 3, h = z & 7;
  const int qt = blockIdx.x, q0 = qt * 16;
  const int t = threadIdx.x, lane = t & 63, w = t >> 6;
  const int fr = lane & 15, fq = lane >> 4;

  // Q fragments (row = fr, k-dim granule = fq*8, 2 chunks of 32 over D=64);
  // all 4 waves load the same 16 rows (L1 broadcast).
  const __bf16* qbase = qkv + ((long)(b << 10) + q0 + fr) * 1536 + h * 64;
  const bf16x8 qf0 = *(const bf16x8*)(qbase + fq * 8);
  const bf16x8 qf1 = *(const bf16x8*)(qbase + 32 + fq * 8);
  const __bf16* kbase = qkv + (long)(b << 10) * 1536 + 512 + h * 64;
  const __bf16* vbase = vT + (long)z * 64 * 1024;

  f32x4 oacc[4] = {};
  float m[4], l[4];
#pragma unroll
  for (int r = 0; r < 4; ++r) { m[r] = -3e38f; l[r] = 0.f; }
  const int myq = q0 + fq * 4;  // C-layout row base for this lane

  __bf16* pw = (__bf16*)&Ob[w][0][0];  // wave-private P tile (alias)
  const int nkv = (MODE == 1) ? (qt >> 2) + 1 : 16;
  for (int kt = w; kt < nkv; kt += 4) {
    const int k0 = kt * 64;
    // ---- S = Q K^T ----
    f32x4 sc[4] = {};
#pragma unroll
    for (int j = 0; j < 4; ++j) {
      const __bf16* kp = kbase + (long)(k0 + j * 16 + fr) * 1536;
      const bf16x8 kf0 = *(const bf16x8*)(kp + fq * 8);
      const bf16x8 kf1 = *(const bf16x8*)(kp + 32 + fq * 8);
      sc[j] = mfma16(qf0, kf0, sc[j]);
      sc[j] = mfma16(qf1, kf1, sc[j]);
    }
    // ---- mask + scale ----
    float sv[4][4];
    if (MODE == 0) {
#pragma unroll
      for (int j = 0; j < 4; ++j) {
        const int km = mask[(b << 10) + k0 + j * 16 + fr];
#pragma unroll
        for (int r = 0; r < 4; ++r)
          sv[j][r] = km != 0 ? sc[j][r] * 0.125f : -1e9f;
      }
    } else {
#pragma unroll
      for (int j = 0; j < 4; ++j) {
        const int kpos = k0 + j * 16 + fr;
#pragma unroll
        for (int r = 0; r < 4; ++r)
          sv[j][r] = kpos <= myq + r ? sc[j][r] * 0.125f : -1e9f;
      }
    }
    // ---- online softmax (rows live across the 16-lane fr dimension) ----
    float p[4][4];
#pragma unroll
    for (int r = 0; r < 4; ++r) {
      float tm = fmaxf(fmaxf(sv[0][r], sv[1][r]), fmaxf(sv[2][r], sv[3][r]));
#pragma unroll
      for (int o = 8; o > 0; o >>= 1) tm = fmaxf(tm, __shfl_xor(tm, o));
      const float mn = fmaxf(m[r], tm);
      const float corr = __expf(m[r] - mn);
      m[r] = mn;
      float rs = 0.f;
#pragma unroll
      for (int j = 0; j < 4; ++j) { p[j][r] = __expf(sv[j][r] - mn); rs += p[j][r]; }
#pragma unroll
      for (int o = 8; o > 0; o >>= 1) rs += __shfl_xor(rs, o);
      l[r] = l[r] * corr + rs;
#pragma unroll
      for (int j = 0; j < 4; ++j) oacc[j][r] *= corr;
    }
    // ---- P -> LDS (granule XOR swizzle, wave-private: no barrier) ----
#pragma unroll
    for (int j = 0; j < 4; ++j) {
      const int c = j >> 1;
      const int gc = (2 * j + (fr >> 3)) & 3;
      const int e = fr & 7;
#pragma unroll
      for (int r = 0; r < 4; ++r) {
        const int row = fq * 4 + r;
        const int slot = c * 4 + (gc ^ ((row >> 1) & 3));
        pw[row * 64 + slot * 8 + e] = (__bf16)p[j][r];
      }
    }
    // ---- O += P V ----
#pragma unroll
    for (int c = 0; c < 2; ++c) {
      const int slot = c * 4 + (fq ^ ((fr >> 1) & 3));
      const bf16x8 pa = *(const bf16x8*)(pw + fr * 64 + slot * 8);
#pragma unroll
      for (int j = 0; j < 4; ++j) {
        const bf16x8 vf = *(const bf16x8*)(vbase + (long)(j * 16 + fr) * 1024 +
                                           k0 + c * 32 + fq * 8);
        oacc[j] = mfma16(pa, vf, oacc[j]);
      }
    }
  }
  __syncthreads();  // all P reads done before Ob f32 overwrite
  // ---- write per-wave partials ----
#pragma unroll
  for (int j = 0; j < 4; ++j)
#pragma unroll
    for (int r = 0; r < 4; ++r) Ob[w][fq * 4 + r][j * 16 + fr] = oacc[j][r];
  if (fr == 0) {
#pragma unroll
    for (int r = 0; r < 4; ++r) { Mw[w][fq * 4 + r] = m[r]; Lw[w][fq * 4 + r] = l[r]; }
  }
  __syncthreads();
  // ---- exact merge of the 4 wave partials; thread t -> row t>>4, 4 cols ----
  const int q = t >> 4, c0 = (t & 15) * 4;
  const float M = fmaxf(fmaxf(Mw[0][q], Mw[1][q]), fmaxf(Mw[2][q], Mw[3][q]));
  const float cf0 = __expf(Mw[0][q] - M), cf1 = __expf(Mw[1][q] - M),
              cf2 = __expf(Mw[2][q] - M), cf3 = __expf(Mw[3][q] - M);
  const float L = cf0 * Lw[0][q] + cf1 * Lw[1][q] +
                  cf2 * Lw[2][q] + cf3 * Lw[3][q];
  const float invL = 1.0f / L;
  __bf16* op = ob + ((long)(b << 10) + q0 + q) * 512 + h * 64 + c0;
#pragma unroll
  for (int cc = 0; cc < 4; ++cc) {
    const float v = cf0 * Ob[0][q][c0 + cc] + cf1 * Ob[1][q][c0 + cc] +
                    cf2 * Ob[2][q][c0 + cc] + cf3 * Ob[3][q][c0 + cc];
    op[cc] = (__bf16)(v * invL);
  }
}

// ---------------------------------------------------------------------------
// batched transpose + f32->bf16: per z, in [R][C] f32 -> out [C][R] bf16.
// Pointer pack (host-precomputed per-z src/dst) batches up to 72 transposes
// into one dispatch (was 17 dispatches).
// ---------------------------------------------------------------------------
struct TPack { const float* s[72]; __bf16* d[72]; };

__global__ __launch_bounds__(256) void transpose_cvt_b(TPack tp, int R, int C) {
  __shared__ __bf16 tile[32][33];
  const float* in = tp.s[blockIdx.z];
  __bf16* out = tp.d[blockIdx.z];
  const int c0 = blockIdx.x * 32, r0 = blockIdx.y * 32;
  const int tc = threadIdx.x & 31, tr = threadIdx.x >> 5;  // 8 rows/pass
#pragma unroll
  for (int j = 0; j < 32; j += 8)
    tile[tr + j][tc] = (__bf16)in[(long)(r0 + tr + j) * C + (c0 + tc)];
  __syncthreads();
#pragma unroll
  for (int j = 0; j < 32; j += 8)
    out[(long)(c0 + tr + j) * R + (r0 + tc)] = tile[tc][tr + j];
}

// ---------------------------------------------------------------------------
// V transpose: qkv[b*S+s][1024 + h*64 + dh] -> vT[(b*8+h)*64 + dh][s]
// ---------------------------------------------------------------------------
__global__ __launch_bounds__(256) void vtrans_kernel(
    const __bf16* __restrict__ qkv, __bf16* __restrict__ vT) {
  __shared__ __bf16 tile[32][33];
  const int z = blockIdx.z, b = z >> 3, h = z & 7;
  const int s0 = blockIdx.x * 32, d0 = blockIdx.y * 32;
  const int tc = threadIdx.x & 31, tr = threadIdx.x >> 5;
  const __bf16* src = qkv + (long)(b << 10) * 1536 + 1024 + h * 64;
#pragma unroll
  for (int j = 0; j < 32; j += 8)
    tile[tr + j][tc] = src[(long)(s0 + tr + j) * 1536 + (d0 + tc)];
  __syncthreads();
  __bf16* dst = vT + (long)z * 64 * 1024;
#pragma unroll
  for (int j = 0; j < 32; j += 8)
    dst[(long)(d0 + tr + j) * 1024 + (s0 + tc)] = tile[tc][tr + j];
}

// ---------------------------------------------------------------------------
__global__ __launch_bounds__(256) void embed_kernel(
    const int* __restrict__ tok, const float* __restrict__ emb,
    float* __restrict__ out) {
  const int bs = blockIdx.x;
  const int spos = bs & (C_S - 1);
  const int tk = tok[bs];
  const float* ep = emb + (long)tk * C_D;
  float* op = out + (long)bs * C_D;
  for (int d = threadIdx.x; d < C_D; d += 256) {
    const int i2 = d & ~1;
    const float freq = __expf((float)i2 * (-9.210340371976184f / 512.0f));
    const float ang = (float)spos * freq;
    const float pe = (d & 1) ? cosf(ang) : sinf(ang);
    op[d] = ep[d] * 22.62741699796952f + pe;
  }
}

__global__ __launch_bounds__(256) void ln_kernel(const float* __restrict__ x,
                                                 __bf16* __restrict__ out) {
  __shared__ float sbuf[4];
  const long row = blockIdx.x;
  const float* xp = x + row * C_D;
  __bf16* op = out + row * C_D;
  const int t = threadIdx.x;
  const float v0 = xp[t];
  const float v1 = xp[t + 256];
  const float mean = block_sum(v0 + v1, sbuf) * (1.0f / 512.0f);
  const float d0 = v0 - mean, d1 = v1 - mean;
  const float ss = block_sum(d0 * d0 + d1 * d1, sbuf);
  const float stdv = sqrtf(ss * (1.0f / 511.0f));
  const float inv = 1.0f / (stdv + C_EPS);
  op[t] = (__bf16)(d0 * inv);
  op[t + 256] = (__bf16)(d1 * inv);
}

// ---------------------------------------------------------------------------
// log_softmax over rows of V=32000 f32, in-place.
// float4 loads (16B/lane), dual online (m,l) states to break the serial
// exp-dependence chain, fully unrolled so loads batch under one vmcnt window.
// Row = 31 float4 iters (31744 elems) + 256-elem scalar tail.
// ---------------------------------------------------------------------------
__global__ __launch_bounds__(256) void logsoftmax_kernel(float* __restrict__ out) {
  __shared__ float sm[4], sl[4];
  const long row = blockIdx.x;
  float* p = out + row * C_V;
  const int t = threadIdx.x, lane = t & 63, w = t >> 6;
  float m0 = -1e30f, l0 = 0.f, m1 = -1e30f, l1 = 0.f;
#pragma unroll
  for (int i = 0; i < 30; i += 2) {
    const f32x4 a = *(const f32x4*)(p + (long)i * 1024 + t * 4);
    const f32x4 b = *(const f32x4*)(p + (long)(i + 1) * 1024 + t * 4);
    {
      const float mx = fmaxf(fmaxf(a[0], a[1]), fmaxf(a[2], a[3]));
      const float mn = fmaxf(m0, mx);
      l0 = l0 * __expf(m0 - mn) +
           ((__expf(a[0] - mn) + __expf(a[1] - mn)) +
            (__expf(a[2] - mn) + __expf(a[3] - mn)));
      m0 = mn;
    }
    {
      const float mx = fmaxf(fmaxf(b[0], b[1]), fmaxf(b[2], b[3]));
      const float mn = fmaxf(m1, mx);
      l1 = l1 * __expf(m1 - mn) +
           ((__expf(b[0] - mn) + __expf(b[1] - mn)) +
            (__expf(b[2] - mn) + __expf(b[3] - mn)));
      m1 = mn;
    }
  }
  {  // vector iter 30
    const f32x4 a = *(const f32x4*)(p + (long)30 * 1024 + t * 4);
    const float mx = fmaxf(fmaxf(a[0], a[1]), fmaxf(a[2], a[3]));
    const float mn = fmaxf(m0, mx);
    l0 = l0 * __expf(m0 - mn) +
         ((__expf(a[0] - mn) + __expf(a[1] - mn)) +
          (__expf(a[2] - mn) + __expf(a[3] - mn)));
    m0 = mn;
  }
  {  // scalar tail: elements 31744..31999
    const float v = p[31744 + t];
    const float mn = fmaxf(m1, v);
    l1 = l1 * __expf(m1 - mn) + __expf(v - mn);
    m1 = mn;
  }
  // merge dual states
  float m = fmaxf(m0, m1);
  float l = l0 * __expf(m0 - m) + l1 * __expf(m1 - m);
#pragma unroll
  for (int o = 32; o > 0; o >>= 1) {
    const float m2 = __shfl_down(m, o), l2 = __shfl_down(l, o);
    const float M = fmaxf(m, m2);
    l = l * __expf(m - M) + l2 * __expf(m2 - M);
    m = M;
  }
  if (lane == 0) { sm[w] = m; sl[w] = l; }
  __syncthreads();
  const float M = fmaxf(fmaxf(sm[0], sm[1]), fmaxf(sm[2], sm[3]));
  const float L = sl[0] * __expf(sm[0] - M) + sl[1] * __expf(sm[1] - M) +
                  sl[2] * __expf(sm[2] - M) + sl[3] * __expf(sm[3] - M);
  const float lz = M + logf(L);
#pragma unroll
  for (int i = 0; i < 31; ++i) {
    f32x4 v = *(const f32x4*)(p + (long)i * 1024 + t * 4);
    v[0] -= lz; v[1] -= lz; v[2] -= lz; v[3] -= lz;
    *(f32x4*)(p + (long)i * 1024 + t * 4) = v;
  }
  p[31744 + t] -= lz;
}

// ---------------------------------------------------------------------------
extern "C" void kernel_launch(void* const* d_in, const int* in_sizes, int n_in,
                              void* d_out, int out_size, void* d_ws,
                              size_t ws_size, hipStream_t stream) {
  (void)in_sizes; (void)n_in; (void)out_size; (void)ws_size;
  const int* src = (const int*)d_in[0];
  const int* tgt = (const int*)d_in[1];
  const int* src_mask = (const int*)d_in[2];
  const int* tgt_mask = (const int*)d_in[3];
  (void)tgt_mask;
  const float* src_emb = (const float*)d_in[4];
  const float* tgt_emb = (const float*)d_in[5];
  const float* in_f[40];
  for (int i = 0; i < 40; ++i) in_f[i] = (const float*)d_in[i];
  float* out = (float*)d_out;

  // ---- workspace carve-up ----
  char* wp = (char*)d_ws;
  auto alloc = [&](size_t bytes) -> char* {
    char* r = wp; wp += (bytes + 255) & ~(size_t)255; return r;
  };
  const long eQKV = (long)6 * 1536 * 512, eDD = (long)6 * 512 * 512,
             eDF = (long)6 * 2048 * 512;
  __bf16* encQKV = (__bf16*)alloc(eQKV * 2);
  __bf16* dsaQKV = (__bf16*)alloc(eQKV * 2);
  __bf16* dcaQKV = (__bf16*)alloc(eQKV * 2);
  __bf16* encWoT = (__bf16*)alloc(eDD * 2);
  __bf16* dsaWoT = (__bf16*)alloc(eDD * 2);
  __bf16* dcaWoT = (__bf16*)alloc(eDD * 2);
  __bf16* encW1T = (__bf16*)alloc(eDF * 2);
  __bf16* encW2T = (__bf16*)alloc(eDF * 2);
  __bf16* decW1T = (__bf16*)alloc(eDF * 2);
  __bf16* decW2T = (__bf16*)alloc(eDF * 2);
  __bf16* projT  = (__bf16*)alloc((long)32000 * 512 * 2);
  float*  x      = (float*)alloc((long)2048 * 512 * 4);
  __bf16* h      = (__bf16*)alloc((long)2048 * 512 * 2);
  __bf16* encb   = (__bf16*)alloc((long)2048 * 512 * 2);
  __bf16* qkv    = (__bf16*)alloc((long)2048 * 1536 * 2);
  __bf16* vT     = (__bf16*)alloc((long)16 * 64 * 1024 * 2);
  __bf16* ob     = (__bf16*)alloc((long)2048 * 512 * 2);
  __bf16* mid    = (__bf16*)alloc((long)2048 * 2048 * 2);

  // ---- weight conversion/transpose, batched (per launch; ws re-poisoned) --
  {
    // 12 D×D weights × 6 layers
    const int si[12] = {6, 8, 10, 12, 18, 20, 22, 24, 26, 28, 30, 32};
    __bf16* db[12] = {encQKV, encQKV, encQKV, encWoT, dsaQKV, dsaQKV, dsaQKV,
                      dsaWoT, dcaQKV, dcaQKV, dcaQKV, dcaWoT};
    const long dstr[12] = {1536 * 512, 1536 * 512, 1536 * 512, 512 * 512,
                           1536 * 512, 1536 * 512, 1536 * 512, 512 * 512,
                           1536 * 512, 1536 * 512, 1536 * 512, 512 * 512};
    const long doff[12] = {0, 512 * 512, 1024 * 512, 0,
                           0, 512 * 512, 1024 * 512, 0,
                           0, 512 * 512, 1024 * 512, 0};
    TPack tp{};
    int n = 0;
    for (int wi = 0; wi < 12; ++wi)
      for (int lz = 0; lz < 6; ++lz, ++n) {
        tp.s[n] = in_f[si[wi]] + (long)lz * 512 * 512;
        tp.d[n] = db[wi] + (long)lz * dstr[wi] + doff[wi];
      }
    transpose_cvt_b<<<dim3(16, 16, 72), 256, 0, stream>>>(tp, 512, 512);
  }
  {
    TPack tp{};  // W1: [512][2048] -> [2048][512]
    for (int lz = 0; lz < 6; ++lz) {
      tp.s[lz] = in_f[14] + (long)lz * 512 * 2048;
      tp.d[lz] = encW1T + (long)lz * 2048 * 512;
      tp.s[6 + lz] = in_f[34] + (long)lz * 512 * 2048;
      tp.d[6 + lz] = decW1T + (long)lz * 2048 * 512;
    }
    transpose_cvt_b<<<dim3(64, 16, 12), 256, 0, stream>>>(tp, 512, 2048);
  }
  {
    TPack tp{};  // W2: [2048][512] -> [512][2048]
    for (int lz = 0; lz < 6; ++lz) {
      tp.s[lz] = in_f[16] + (long)lz * 2048 * 512;
      tp.d[lz] = encW2T + (long)lz * 2048 * 512;
      tp.s[6 + lz] = in_f[36] + (long)lz * 2048 * 512;
      tp.d[6 + lz] = decW2T + (long)lz * 2048 * 512;
    }
    transpose_cvt_b<<<dim3(16, 64, 12), 256, 0, stream>>>(tp, 2048, 512);
  }
  {
    TPack tp{};  // proj: [512][32000] -> [32000][512]
    tp.s[0] = in_f[38];
    tp.d[0] = projT;
    transpose_cvt_b<<<dim3(1000, 16, 1), 256, 0, stream>>>(tp, 512, 32000);
  }

  auto attn_core = [&](const int* mask, int mode, const __bf16* woT_l,
                       const float* bo_l) {
    vtrans_kernel<<<dim3(32, 2, 16), 256, 0, stream>>>(qkv, vT);
    if (mode == 0)
      flash_attn<0><<<dim3(64, 16), 256, 0, stream>>>(qkv, vT, mask, ob);
    else
      flash_attn<1><<<dim3(64, 16), 256, 0, stream>>>(qkv, vT, mask, ob);
    // x += O Wo + bo   (split-K 2, atomic)
    gemm_bt<64, 64, 4, false, false><<<dim3(8, 32, 2), 256, 0, stream>>>(
        ob, 512, 256, 0, woT_l, 512, 256, 0, x, 512, 0, 0, bo_l, nullptr,
        nullptr, 256, 1, 1.f);
  };

  auto ffn = [&](const __bf16* w1T_l, const float* b1_l, const __bf16* w2T_l,
                 const float* b2_l) {
    gemm_bt<128, 64, 1, false, false><<<dim3(32, 16, 1), 256, 0, stream>>>(
        h, 512, 0, 0, w1T_l, 512, 0, 0, mid, 2048, 0, 0, b1_l, nullptr,
        nullptr, 512, 1, 1.f);
    gemm_bt<64, 64, 4, false, false><<<dim3(8, 32, 2), 256, 0, stream>>>(
        mid, 2048, 1024, 0, w2T_l, 2048, 1024, 0, x, 512, 0, 0, b2_l, nullptr,
        nullptr, 1024, 1, 1.f);
  };

  const int rows = C_B * C_S;

  // ================= encoder =================
  embed_kernel<<<rows, 256, 0, stream>>>(src, src_emb, x);
  for (int i = 0; i < C_L; ++i) {
    const long oW = (long)i * 1536 * 512, oB = (long)i * 512;
    ln_kernel<<<rows, 256, 0, stream>>>(x, h);
    gemm_bt<128, 64, 0, true, false><<<dim3(24, 16, 1), 256, 0, stream>>>(
        h, 512, 0, 0, encQKV + oW, 512, 0, 0, qkv, 1536, 0, 0,
        in_f[7] + oB, in_f[9] + oB, in_f[11] + oB, 512, 1, 1.f);
    attn_core(src_mask, 0, encWoT + (long)i * 512 * 512, in_f[13] + oB);
    ln_kernel<<<rows, 256, 0, stream>>>(x, h);
    ffn(encW1T + (long)i * 2048 * 512, in_f[15] + (long)i * 2048,
        encW2T + (long)i * 2048 * 512, in_f[17] + oB);
  }
  ln_kernel<<<rows, 256, 0, stream>>>(x, encb);

  // ================= decoder =================
  embed_kernel<<<rows, 256, 0, stream>>>(tgt, tgt_emb, x);
  for (int i = 0; i < C_L; ++i) {
    const long oW = (long)i * 1536 * 512, oB = (long)i * 512;
    // self-attn (reference quirk: src_mask)
    ln_kernel<<<rows, 256, 0, stream>>>(x, h);
    gemm_bt<128, 64, 0, true, false><<<dim3(24, 16, 1), 256, 0, stream>>>(
        h, 512, 0, 0, dsaQKV + oW, 512, 0, 0, qkv, 1536, 0, 0,
        in_f[19] + oB, in_f[21] + oB, in_f[23] + oB, 512, 1, 1.f);
    attn_core(src_mask, 0, dsaWoT + (long)i * 512 * 512, in_f[25] + oB);
    // cross-attn (reference quirk: tgt_mask = causal); Q from h, K/V from encb
    ln_kernel<<<rows, 256, 0, stream>>>(x, h);
    gemm_bt<64, 64, 0, false, false><<<dim3(8, 32, 1), 256, 0, stream>>>(
        h, 512, 0, 0, dcaQKV + oW, 512, 0, 0, qkv, 1536, 0, 0,
        in_f[27] + oB, nullptr, nullptr, 512, 1, 1.f);
    gemm_bt<128, 64, 0, true, false><<<dim3(16, 16, 1), 256, 0, stream>>>(
        encb, 512, 0, 0, dcaQKV + oW + (long)512 * 512, 512, 0, 0, qkv + 512,
        1536, 0, 0, in_f[29] + oB, in_f[31] + oB, nullptr, 512, 1, 1.f);
    attn_core(nullptr, 1, dcaWoT + (long)i * 512 * 512, in_f[33] + oB);
    ln_kernel<<<rows, 256, 0, stream>>>(x, h);
    ffn(decW1T + (long)i * 2048 * 512, in_f[35] + (long)i * 2048,
        decW2T + (long)i * 2048 * 512, in_f[37] + oB);
  }
  ln_kernel<<<rows, 256, 0, stream>>>(x, h);

  // ---- final projection (SWAP grid: M-major for proj_w L2 reuse) ----
  gemm_bt<128, 128, 3, false, true><<<dim3(16, 250, 1), 256, 0, stream>>>(
      h, 512, 0, 0, projT, 512, 0, 0, out, 32000, 0, 0, in_f[39], nullptr,
      nullptr, 512, 1, 1.f);
  logsoftmax_kernel<<<rows, 256, 0, stream>>>(out);
}

// Round 5
// 2341.899 us; speedup vs baseline: 1.2270x; 1.0686x over previous
//
#include <hip/hip_runtime.h>
#include <math.h>

constexpr int C_B = 2, C_S = 1024, C_D = 512, C_H = 8, C_DH = 64,
              C_F = 2048, C_L = 6, C_V = 32000;
constexpr float C_EPS = 1e-6f;

using bf16x8 = __attribute__((ext_vector_type(8))) __bf16;
using bf16x4v = __attribute__((ext_vector_type(4))) __bf16;
using f32x4  = __attribute__((ext_vector_type(4))) float;

__device__ __forceinline__ f32x4 mfma16(bf16x8 a, bf16x8 b, f32x4 c) {
  return __builtin_amdgcn_mfma_f32_16x16x32_bf16(a, b, c, 0, 0, 0);
}

__device__ __forceinline__ void async16(const __bf16* g, __bf16* l) {
  __builtin_amdgcn_global_load_lds(
      (const __attribute__((address_space(1))) void*)g,
      (__attribute__((address_space(3))) void*)l, 16, 0, 0);
}

__device__ __forceinline__ float block_sum(float v, float* sbuf) {
#pragma unroll
  for (int o = 32; o > 0; o >>= 1) v += __shfl_down(v, o);
  __syncthreads();
  if ((threadIdx.x & 63) == 0) sbuf[threadIdx.x >> 6] = v;
  __syncthreads();
  return (sbuf[0] + sbuf[1]) + (sbuf[2] + sbuf[3]);
}

// ---------------------------------------------------------------------------
// bf16 GEMM, B in [N][K] layout. C[M,N] = scale*(A@B^T) + bias, epilogues:
// EPI 0: store bf16; 1: store bf16+relu; 3: store f32; 4: f32 atomicAdd
// (residual, bias only when zb==0; z = K-split index via sAb/sBb k-offsets).
// TRI: bias segmented per 512 cols (b0/b1/b2). SWAP: m from blockIdx.x.
// bstr: per-zb bias stride (batched-layer dispatches; 0 = shared bias).
// global_load_lds staging (16B/lane), XOR granule swizzle in LDS.
// 2-phase double-buffered pipeline: STAGE(next) issued before compute(cur).
// ---------------------------------------------------------------------------
template <int BM, int BN, int EPI, bool TRI, bool SWAP>
__global__ __launch_bounds__(256) void gemm_bt(
    const __bf16* __restrict__ A, int lda, long sAb, long sAh,
    const __bf16* __restrict__ B, int ldb, long sBb, long sBh,
    void* __restrict__ Cv, int ldc, long sCb, long sCh,
    const float* __restrict__ b0, const float* __restrict__ b1,
    const float* __restrict__ b2, int bstr, int K, int hdim, float scale) {
  constexpr int BK = 32;
  __shared__ __bf16 As[2][BM][BK];
  __shared__ __bf16 Bs[2][BN][BK];
  const int z = blockIdx.z;
  const int zb = z / hdim, zh = z - zb * hdim;
  const __bf16* Ap = A + (long)zb * sAb + (long)zh * sAh;
  const __bf16* Bp = B + (long)zb * sBb + (long)zh * sBh;
  const int m0 = (SWAP ? blockIdx.x : blockIdx.y) * BM;
  const int n0 = (SWAP ? blockIdx.y : blockIdx.x) * BN;
  const int t = threadIdx.x, lane = t & 63, w = t >> 6;
  const int wr = w >> 1, wc = w & 1;
  constexpr int WM = BM / 2, WN = BN / 2, TM = WM / 16, TN = WN / 16;
  constexpr int AI = BM / 64, BI = BN / 64;
  const int srow = lane >> 2;       // row within 16-row staging group
  const int sg = lane & 3;          // LDS granule this lane fills
  const int fr = lane & 15, fq = lane >> 4;

  auto stage = [&](int buf, int k0) {
#pragma unroll
    for (int j = 0; j < AI; ++j) {
      const int r0 = w * (AI * 16) + j * 16;
      const int row = r0 + srow;
      const int s = sg ^ ((row >> 1) & 3);  // global k-seg for this granule
      async16(Ap + (long)(m0 + row) * lda + (k0 + s * 8), &As[buf][r0][0]);
    }
#pragma unroll
    for (int j = 0; j < BI; ++j) {
      const int r0 = w * (BI * 16) + j * 16;
      const int row = r0 + srow;
      const int s = sg ^ ((row >> 1) & 3);
      async16(Bp + (long)(n0 + row) * ldb + (k0 + s * 8), &Bs[buf][r0][0]);
    }
  };

  f32x4 acc[TM][TN] = {};
  const int nt = K / BK;
  stage(0, 0);
  __syncthreads();  // compiler drains vmcnt(0) before s_barrier
  int cur = 0;
  for (int ti = 0; ti < nt; ++ti) {
    if (ti + 1 < nt) stage(cur ^ 1, (ti + 1) * BK);  // fly during MFMAs
    bf16x8 af[TM], bfr[TN];
#pragma unroll
    for (int i = 0; i < TM; ++i) {
      const int row = wr * WM + i * 16 + fr;
      const int g = fq ^ ((row >> 1) & 3);
      af[i] = *(const bf16x8*)&As[cur][row][g * 8];
    }
#pragma unroll
    for (int i = 0; i < TN; ++i) {
      const int row = wc * WN + i * 16 + fr;
      const int g = fq ^ ((row >> 1) & 3);
      bfr[i] = *(const bf16x8*)&Bs[cur][row][g * 8];
    }
#pragma unroll
    for (int i = 0; i < TM; ++i)
#pragma unroll
      for (int j = 0; j < TN; ++j) acc[i][j] = mfma16(af[i], bfr[j], acc[i][j]);
    __syncthreads();  // drains next-tile loads (overlapped) + syncs reuse
    cur ^= 1;
  }

  const long co = (long)zb * sCb + (long)zh * sCh;
  const int rq = (lane >> 4) * 4;
#pragma unroll
  for (int i = 0; i < TM; ++i) {
#pragma unroll
    for (int j = 0; j < TN; ++j) {
      const int colg = n0 + wc * WN + j * 16 + fr;
      float bv = 0.f;
      if (b0) {
        if (TRI) {
          const float* bp = colg < 512 ? b0 : (colg < 1024 ? b1 : b2);
          bv = bp[zb * bstr + (colg & 511)];
        } else {
          bv = b0[zb * bstr + colg];
        }
      }
      if (EPI == 4 && zb != 0) bv = 0.f;
#pragma unroll
      for (int r = 0; r < 4; ++r) {
        const int rowg = m0 + wr * WM + i * 16 + rq + r;
        const long ci = co + (long)rowg * ldc + colg;
        float v = acc[i][j][r] * scale + bv;
        if (EPI == 0) ((__bf16*)Cv)[ci] = (__bf16)v;
        else if (EPI == 1) ((__bf16*)Cv)[ci] = (__bf16)fmaxf(v, 0.f);
        else if (EPI == 3) ((float*)Cv)[ci] = v;
        else atomicAdd((float*)Cv + ci, v);
      }
    }
  }
}

// ---------------------------------------------------------------------------
// Fused flash attention, KV-split, with in-kernel V transpose (no vT buffer).
// Q from qkv[b*S+s][1536]; K at kvsrc + b*kvBatch + h*64 + s*kvStride;
// V at the same address + 512. Output ob[b*S+s][h*64+dh] bf16.
// Grid: x = 16-row q-tile (64), y = b*8+h -> 1024 blocks, 4 blocks/CU.
// Wave w owns KV tiles kt = w, w+4, ... with private (m,l,O); exact LDS merge.
// Per tile: V tile (64 s x 64 dh) DMA'd via global_load_lds into a
// wave-private LDS quadrant (linear layout - DMA dest is base+lane*16),
// issued at tile top so HBM/L2 latency hides under QK^T+softmax (T14).
// PV assembles V^T fragments by transpose-reading LDS (ds_read_u16, ~4-way
// conflicts - cheap). Explicit vmcnt(0)+sched_barrier before the reads:
// the compiler cannot see the DMA->ds_read dependency.
// LDS union: loop {P 8KB + V 32KB} | merge {Ob 16KB + stats} = 40960 B.
// MODE 0: key mask from mask[b][k]. MODE 1: analytic causal (tril).
// ---------------------------------------------------------------------------
struct FlashLP { __bf16 P[4][16][64]; __bf16 V[4][64][64]; };
struct FlashMG { float O[4][16][64]; float M[4][16]; float L[4][16]; };
union FlashU { FlashLP lp; FlashMG mg; };

template <int MODE>
__global__ __launch_bounds__(256) void flash_attn(
    const __bf16* __restrict__ qkv, const __bf16* __restrict__ kvsrc,
    long kvBatch, int kvStride, const int* __restrict__ mask,
    __bf16* __restrict__ ob) {
  __shared__ FlashU U;
  const int z = blockIdx.y, b = z >> 3, h = z & 7;
  const int qt = blockIdx.x, q0 = qt * 16;
  const int t = threadIdx.x, lane = t & 63, w = t >> 6;
  const int fr = lane & 15, fq = lane >> 4;

  // Q fragments (row = fr, k-dim granule = fq*8, 2 chunks of 32 over D=64)
  const __bf16* qbase = qkv + ((long)(b << 10) + q0 + fr) * 1536 + h * 64;
  const bf16x8 qf0 = *(const bf16x8*)(qbase + fq * 8);
  const bf16x8 qf1 = *(const bf16x8*)(qbase + 32 + fq * 8);
  const __bf16* kvp = kvsrc + (long)b * kvBatch + h * 64;

  f32x4 oacc[4] = {};
  float m[4], l[4];
#pragma unroll
  for (int r = 0; r < 4; ++r) { m[r] = -3e38f; l[r] = 0.f; }
  const int myq = q0 + fq * 4;  // C-layout row base for this lane

  __bf16* pw = &U.lp.P[w][0][0];
  __bf16* vw = &U.lp.V[w][0][0];
  const int vrow = lane >> 3, vcol = (lane & 7) * 8;  // V staging lane map
  const int nkv = (MODE == 1) ? (qt >> 2) + 1 : 16;
  for (int kt = w; kt < nkv; kt += 4) {
    const int k0 = kt * 64;
    // ---- V tile DMA (lands before the vmcnt(0) below) ----
    __builtin_amdgcn_sched_barrier(0);
#pragma unroll
    for (int ro = 0; ro < 8; ++ro)
      async16(kvp + 512 + (long)(k0 + ro * 8 + vrow) * kvStride + vcol,
              vw + ro * 512);
    // ---- S = Q K^T ----
    f32x4 sc[4] = {};
#pragma unroll
    for (int j = 0; j < 4; ++j) {
      const __bf16* kp = kvp + (long)(k0 + j * 16 + fr) * kvStride;
      const bf16x8 kf0 = *(const bf16x8*)(kp + fq * 8);
      const bf16x8 kf1 = *(const bf16x8*)(kp + 32 + fq * 8);
      sc[j] = mfma16(qf0, kf0, sc[j]);
      sc[j] = mfma16(qf1, kf1, sc[j]);
    }
    // ---- mask + scale ----
    float sv[4][4];
    if (MODE == 0) {
#pragma unroll
      for (int j = 0; j < 4; ++j) {
        const int km = mask[(b << 10) + k0 + j * 16 + fr];
#pragma unroll
        for (int r = 0; r < 4; ++r)
          sv[j][r] = km != 0 ? sc[j][r] * 0.125f : -1e9f;
      }
    } else {
#pragma unroll
      for (int j = 0; j < 4; ++j) {
        const int kpos = k0 + j * 16 + fr;
#pragma unroll
        for (int r = 0; r < 4; ++r)
          sv[j][r] = kpos <= myq + r ? sc[j][r] * 0.125f : -1e9f;
      }
    }
    // ---- online softmax (rows live across the 16-lane fr dimension) ----
    float p[4][4];
#pragma unroll
    for (int r = 0; r < 4; ++r) {
      float tm = fmaxf(fmaxf(sv[0][r], sv[1][r]), fmaxf(sv[2][r], sv[3][r]));
#pragma unroll
      for (int o = 8; o > 0; o >>= 1) tm = fmaxf(tm, __shfl_xor(tm, o));
      const float mn = fmaxf(m[r], tm);
      const float corr = __expf(m[r] - mn);
      m[r] = mn;
      float rs = 0.f;
#pragma unroll
      for (int j = 0; j < 4; ++j) { p[j][r] = __expf(sv[j][r] - mn); rs += p[j][r]; }
#pragma unroll
      for (int o = 8; o > 0; o >>= 1) rs += __shfl_xor(rs, o);
      l[r] = l[r] * corr + rs;
#pragma unroll
      for (int j = 0; j < 4; ++j) oacc[j][r] *= corr;
    }
    // ---- P -> LDS (granule XOR swizzle, wave-private: no barrier) ----
#pragma unroll
    for (int j = 0; j < 4; ++j) {
      const int c = j >> 1;
      const int gc = (2 * j + (fr >> 3)) & 3;
      const int e = fr & 7;
#pragma unroll
      for (int r = 0; r < 4; ++r) {
        const int row = fq * 4 + r;
        const int slot = c * 4 + (gc ^ ((row >> 1) & 3));
        pw[row * 64 + slot * 8 + e] = (__bf16)p[j][r];
      }
    }
    // ---- wait V DMA; compiler cannot see this dependency ----
    __builtin_amdgcn_sched_barrier(0);
    asm volatile("s_waitcnt vmcnt(0)" ::: "memory");
    __builtin_amdgcn_sched_barrier(0);
    // ---- O += P V  (V^T fragments via LDS transpose reads) ----
#pragma unroll
    for (int c = 0; c < 2; ++c) {
      const int slot = c * 4 + (fq ^ ((fr >> 1) & 3));
      const bf16x8 pa = *(const bf16x8*)(pw + fr * 64 + slot * 8);
#pragma unroll
      for (int j = 0; j < 4; ++j) {
        bf16x8 vf;
#pragma unroll
        for (int e = 0; e < 8; ++e)
          vf[e] = vw[(c * 32 + fq * 8 + e) * 64 + (j * 16 + fr)];
        oacc[j] = mfma16(pa, vf, oacc[j]);
      }
    }
  }
  __syncthreads();  // all waves' LDS reads done before merge overwrite
  // ---- write per-wave partials ----
#pragma unroll
  for (int j = 0; j < 4; ++j)
#pragma unroll
    for (int r = 0; r < 4; ++r) U.mg.O[w][fq * 4 + r][j * 16 + fr] = oacc[j][r];
  if (fr == 0) {
#pragma unroll
    for (int r = 0; r < 4; ++r) {
      U.mg.M[w][fq * 4 + r] = m[r];
      U.mg.L[w][fq * 4 + r] = l[r];
    }
  }
  __syncthreads();
  // ---- exact merge of the 4 wave partials; thread t -> row t>>4, 4 cols ----
  const int q = t >> 4, c0 = (t & 15) * 4;
  const float M = fmaxf(fmaxf(U.mg.M[0][q], U.mg.M[1][q]),
                        fmaxf(U.mg.M[2][q], U.mg.M[3][q]));
  const float cf0 = __expf(U.mg.M[0][q] - M), cf1 = __expf(U.mg.M[1][q] - M),
              cf2 = __expf(U.mg.M[2][q] - M), cf3 = __expf(U.mg.M[3][q] - M);
  const float L = cf0 * U.mg.L[0][q] + cf1 * U.mg.L[1][q] +
                  cf2 * U.mg.L[2][q] + cf3 * U.mg.L[3][q];
  const float invL = 1.0f / L;
  __bf16* op = ob + ((long)(b << 10) + q0 + q) * 512 + h * 64 + c0;
#pragma unroll
  for (int cc = 0; cc < 4; ++cc) {
    const float v = cf0 * U.mg.O[0][q][c0 + cc] + cf1 * U.mg.O[1][q][c0 + cc] +
                    cf2 * U.mg.O[2][q][c0 + cc] + cf3 * U.mg.O[3][q][c0 + cc];
    op[cc] = (__bf16)(v * invL);
  }
}

// ---------------------------------------------------------------------------
// batched transpose + f32->bf16: per z, in [R][C] f32 -> out [C][R] bf16.
// ---------------------------------------------------------------------------
struct TPack { const float* s[72]; __bf16* d[72]; };

__global__ __launch_bounds__(256) void transpose_cvt_b(TPack tp, int R, int C) {
  __shared__ __bf16 tile[32][33];
  const float* in = tp.s[blockIdx.z];
  __bf16* out = tp.d[blockIdx.z];
  const int c0 = blockIdx.x * 32, r0 = blockIdx.y * 32;
  const int tc = threadIdx.x & 31, tr = threadIdx.x >> 5;  // 8 rows/pass
#pragma unroll
  for (int j = 0; j < 32; j += 8)
    tile[tr + j][tc] = (__bf16)in[(long)(r0 + tr + j) * C + (c0 + tc)];
  __syncthreads();
#pragma unroll
  for (int j = 0; j < 32; j += 8)
    out[(long)(c0 + tr + j) * R + (r0 + tc)] = tile[tc][tr + j];
}

// ---------------------------------------------------------------------------
// fused embedding + positional encoding + first LayerNorm:
// writes residual stream x (f32) and normalized h (bf16) in one pass.
// ---------------------------------------------------------------------------
__global__ __launch_bounds__(256) void embed_ln(
    const int* __restrict__ tok, const float* __restrict__ emb,
    float* __restrict__ x, __bf16* __restrict__ hout) {
  __shared__ float sbuf[4];
  const int bs = blockIdx.x;
  const int spos = bs & (C_S - 1);
  const int tk = tok[bs];
  const float* ep = emb + (long)tk * C_D;
  float* op = x + (long)bs * C_D;
  __bf16* hp = hout + (long)bs * C_D;
  const int t = threadIdx.x;
  float v[2];
#pragma unroll
  for (int k = 0; k < 2; ++k) {
    const int d = t + k * 256;
    const int i2 = d & ~1;
    const float freq = __expf((float)i2 * (-9.210340371976184f / 512.0f));
    const float ang = (float)spos * freq;
    const float pe = (d & 1) ? cosf(ang) : sinf(ang);
    v[k] = ep[d] * 22.62741699796952f + pe;
    op[d] = v[k];
  }
  const float mean = block_sum(v[0] + v[1], sbuf) * (1.0f / 512.0f);
  const float d0 = v[0] - mean, d1 = v[1] - mean;
  const float ss = block_sum(d0 * d0 + d1 * d1, sbuf);
  const float inv = 1.0f / (sqrtf(ss * (1.0f / 511.0f)) + C_EPS);
  hp[t] = (__bf16)(d0 * inv);
  hp[t + 256] = (__bf16)(d1 * inv);
}

__global__ __launch_bounds__(256) void ln_kernel(const float* __restrict__ x,
                                                 __bf16* __restrict__ out) {
  __shared__ float sbuf[4];
  const long row = blockIdx.x;
  const float* xp = x + row * C_D;
  __bf16* op = out + row * C_D;
  const int t = threadIdx.x;
  const float v0 = xp[t];
  const float v1 = xp[t + 256];
  const float mean = block_sum(v0 + v1, sbuf) * (1.0f / 512.0f);
  const float d0 = v0 - mean, d1 = v1 - mean;
  const float ss = block_sum(d0 * d0 + d1 * d1, sbuf);
  const float stdv = sqrtf(ss * (1.0f / 511.0f));
  const float inv = 1.0f / (stdv + C_EPS);
  op[t] = (__bf16)(d0 * inv);
  op[t + 256] = (__bf16)(d1 * inv);
}

// ---------------------------------------------------------------------------
// log_softmax over rows of V=32000 f32, in-place. float4 loads, dual online
// (m,l) states, fully unrolled. 31 float4 iters + 256-elem scalar tail.
// ---------------------------------------------------------------------------
__global__ __launch_bounds__(256) void logsoftmax_kernel(float* __restrict__ out) {
  __shared__ float sm[4], sl[4];
  const long row = blockIdx.x;
  float* p = out + row * C_V;
  const int t = threadIdx.x, lane = t & 63, w = t >> 6;
  float m0 = -1e30f, l0 = 0.f, m1 = -1e30f, l1 = 0.f;
#pragma unroll
  for (int i = 0; i < 30; i += 2) {
    const f32x4 a = *(const f32x4*)(p + (long)i * 1024 + t * 4);
    const f32x4 b = *(const f32x4*)(p + (long)(i + 1) * 1024 + t * 4);
    {
      const float mx = fmaxf(fmaxf(a[0], a[1]), fmaxf(a[2], a[3]));
      const float mn = fmaxf(m0, mx);
      l0 = l0 * __expf(m0 - mn) +
           ((__expf(a[0] - mn) + __expf(a[1] - mn)) +
            (__expf(a[2] - mn) + __expf(a[3] - mn)));
      m0 = mn;
    }
    {
      const float mx = fmaxf(fmaxf(b[0], b[1]), fmaxf(b[2], b[3]));
      const float mn = fmaxf(m1, mx);
      l1 = l1 * __expf(m1 - mn) +
           ((__expf(b[0] - mn) + __expf(b[1] - mn)) +
            (__expf(b[2] - mn) + __expf(b[3] - mn)));
      m1 = mn;
    }
  }
  {  // vector iter 30
    const f32x4 a = *(const f32x4*)(p + (long)30 * 1024 + t * 4);
    const float mx = fmaxf(fmaxf(a[0], a[1]), fmaxf(a[2], a[3]));
    const float mn = fmaxf(m0, mx);
    l0 = l0 * __expf(m0 - mn) +
         ((__expf(a[0] - mn) + __expf(a[1] - mn)) +
          (__expf(a[2] - mn) + __expf(a[3] - mn)));
    m0 = mn;
  }
  {  // scalar tail: elements 31744..31999
    const float v = p[31744 + t];
    const float mn = fmaxf(m1, v);
    l1 = l1 * __expf(m1 - mn) + __expf(v - mn);
    m1 = mn;
  }
  float m = fmaxf(m0, m1);
  float l = l0 * __expf(m0 - m) + l1 * __expf(m1 - m);
#pragma unroll
  for (int o = 32; o > 0; o >>= 1) {
    const float m2 = __shfl_down(m, o), l2 = __shfl_down(l, o);
    const float M = fmaxf(m, m2);
    l = l * __expf(m - M) + l2 * __expf(m2 - M);
    m = M;
  }
  if (lane == 0) { sm[w] = m; sl[w] = l; }
  __syncthreads();
  const float M = fmaxf(fmaxf(sm[0], sm[1]), fmaxf(sm[2], sm[3]));
  const float L = sl[0] * __expf(sm[0] - M) + sl[1] * __expf(sm[1] - M) +
                  sl[2] * __expf(sm[2] - M) + sl[3] * __expf(sm[3] - M);
  const float lz = M + logf(L);
#pragma unroll
  for (int i = 0; i < 31; ++i) {
    f32x4 v = *(const f32x4*)(p + (long)i * 1024 + t * 4);
    v[0] -= lz; v[1] -= lz; v[2] -= lz; v[3] -= lz;
    *(f32x4*)(p + (long)i * 1024 + t * 4) = v;
  }
  p[31744 + t] -= lz;
}

// ---------------------------------------------------------------------------
extern "C" void kernel_launch(void* const* d_in, const int* in_sizes, int n_in,
                              void* d_out, int out_size, void* d_ws,
                              size_t ws_size, hipStream_t stream) {
  (void)in_sizes; (void)n_in; (void)out_size; (void)ws_size;
  const int* src = (const int*)d_in[0];
  const int* tgt = (const int*)d_in[1];
  const int* src_mask = (const int*)d_in[2];
  const int* tgt_mask = (const int*)d_in[3];
  (void)tgt_mask;
  const float* src_emb = (const float*)d_in[4];
  const float* tgt_emb = (const float*)d_in[5];
  const float* in_f[40];
  for (int i = 0; i < 40; ++i) in_f[i] = (const float*)d_in[i];
  float* out = (float*)d_out;

  // ---- workspace carve-up ----
  char* wp = (char*)d_ws;
  auto alloc = [&](size_t bytes) -> char* {
    char* r = wp; wp += (bytes + 255) & ~(size_t)255; return r;
  };
  const long eQKV = (long)6 * 1536 * 512, eDD = (long)6 * 512 * 512,
             eDF = (long)6 * 2048 * 512;
  __bf16* encQKV = (__bf16*)alloc(eQKV * 2);
  __bf16* dsaQKV = (__bf16*)alloc(eQKV * 2);
  __bf16* dcaQKV = (__bf16*)alloc(eQKV * 2);
  __bf16* encWoT = (__bf16*)alloc(eDD * 2);
  __bf16* dsaWoT = (__bf16*)alloc(eDD * 2);
  __bf16* dcaWoT = (__bf16*)alloc(eDD * 2);
  __bf16* encW1T = (__bf16*)alloc(eDF * 2);
  __bf16* encW2T = (__bf16*)alloc(eDF * 2);
  __bf16* decW1T = (__bf16*)alloc(eDF * 2);
  __bf16* decW2T = (__bf16*)alloc(eDF * 2);
  __bf16* projT  = (__bf16*)alloc((long)32000 * 512 * 2);
  float*  x      = (float*)alloc((long)2048 * 512 * 4);
  __bf16* h      = (__bf16*)alloc((long)2048 * 512 * 2);
  __bf16* encb   = (__bf16*)alloc((long)2048 * 512 * 2);
  __bf16* qkv    = (__bf16*)alloc((long)2048 * 1536 * 2);
  __bf16* ob     = (__bf16*)alloc((long)2048 * 512 * 2);
  __bf16* mid    = (__bf16*)alloc((long)2048 * 2048 * 2);
  __bf16* dcaKVb = (__bf16*)alloc((long)6 * 2048 * 1024 * 2);

  // ---- weight conversion/transpose, batched ----
  {
    const int si[12] = {6, 8, 10, 12, 18, 20, 22, 24, 26, 28, 30, 32};
    __bf16* db[12] = {encQKV, encQKV, encQKV, encWoT, dsaQKV, dsaQKV, dsaQKV,
                      dsaWoT, dcaQKV, dcaQKV, dcaQKV, dcaWoT};
    const long dstr[12] = {1536 * 512, 1536 * 512, 1536 * 512, 512 * 512,
                           1536 * 512, 1536 * 512, 1536 * 512, 512 * 512,
                           1536 * 512, 1536 * 512, 1536 * 512, 512 * 512};
    const long doff[12] = {0, 512 * 512, 1024 * 512, 0,
                           0, 512 * 512, 1024 * 512, 0,
                           0, 512 * 512, 1024 * 512, 0};
    TPack tp{};
    int n = 0;
    for (int wi = 0; wi < 12; ++wi)
      for (int lz = 0; lz < 6; ++lz, ++n) {
        tp.s[n] = in_f[si[wi]] + (long)lz * 512 * 512;
        tp.d[n] = db[wi] + (long)lz * dstr[wi] + doff[wi];
      }
    transpose_cvt_b<<<dim3(16, 16, 72), 256, 0, stream>>>(tp, 512, 512);
  }
  {
    TPack tp{};  // W1: [512][2048] -> [2048][512]
    for (int lz = 0; lz < 6; ++lz) {
      tp.s[lz] = in_f[14] + (long)lz * 512 * 2048;
      tp.d[lz] = encW1T + (long)lz * 2048 * 512;
      tp.s[6 + lz] = in_f[34] + (long)lz * 512 * 2048;
      tp.d[6 + lz] = decW1T + (long)lz * 2048 * 512;
    }
    transpose_cvt_b<<<dim3(64, 16, 12), 256, 0, stream>>>(tp, 512, 2048);
  }
  {
    TPack tp{};  // W2: [2048][512] -> [512][2048]
    for (int lz = 0; lz < 6; ++lz) {
      tp.s[lz] = in_f[16] + (long)lz * 2048 * 512;
      tp.d[lz] = encW2T + (long)lz * 2048 * 512;
      tp.s[6 + lz] = in_f[36] + (long)lz * 2048 * 512;
      tp.d[6 + lz] = decW2T + (long)lz * 2048 * 512;
    }
    transpose_cvt_b<<<dim3(16, 64, 12), 256, 0, stream>>>(tp, 2048, 512);
  }
  {
    TPack tp{};  // proj: [512][32000] -> [32000][512]
    tp.s[0] = in_f[38];
    tp.d[0] = projT;
    transpose_cvt_b<<<dim3(1000, 16, 1), 256, 0, stream>>>(tp, 512, 32000);
  }

  auto attn_out = [&](const __bf16* woT_l, const float* bo_l) {
    // x += O Wo + bo   (split-K 2, atomic)
    gemm_bt<64, 64, 4, false, false><<<dim3(8, 32, 2), 256, 0, stream>>>(
        ob, 512, 256, 0, woT_l, 512, 256, 0, x, 512, 0, 0, bo_l, nullptr,
        nullptr, 0, 256, 1, 1.f);
  };

  auto ffn = [&](const __bf16* w1T_l, const float* b1_l, const __bf16* w2T_l,
                 const float* b2_l) {
    gemm_bt<128, 64, 1, false, false><<<dim3(32, 16, 1), 256, 0, stream>>>(
        h, 512, 0, 0, w1T_l, 512, 0, 0, mid, 2048, 0, 0, b1_l, nullptr,
        nullptr, 0, 512, 1, 1.f);
    gemm_bt<64, 64, 4, false, false><<<dim3(8, 32, 2), 256, 0, stream>>>(
        mid, 2048, 1024, 0, w2T_l, 2048, 1024, 0, x, 512, 0, 0, b2_l, nullptr,
        nullptr, 0, 1024, 1, 1.f);
  };

  const int rows = C_B * C_S;
  const long selfKVB = (long)1024 * 1536;

  // ================= encoder =================
  embed_ln<<<rows, 256, 0, stream>>>(src, src_emb, x, h);
  for (int i = 0; i < C_L; ++i) {
    const long oW = (long)i * 1536 * 512, oB = (long)i * 512;
    gemm_bt<128, 64, 0, true, false><<<dim3(24, 16, 1), 256, 0, stream>>>(
        h, 512, 0, 0, encQKV + oW, 512, 0, 0, qkv, 1536, 0, 0,
        in_f[7] + oB, in_f[9] + oB, in_f[11] + oB, 0, 512, 1, 1.f);
    flash_attn<0><<<dim3(64, 16), 256, 0, stream>>>(qkv, qkv + 512, selfKVB,
                                                    1536, src_mask, ob);
    attn_out(encWoT + (long)i * 512 * 512, in_f[13] + oB);
    ln_kernel<<<rows, 256, 0, stream>>>(x, h);
    ffn(encW1T + (long)i * 2048 * 512, in_f[15] + (long)i * 2048,
        encW2T + (long)i * 2048 * 512, in_f[17] + oB);
    ln_kernel<<<rows, 256, 0, stream>>>(x, i < C_L - 1 ? h : encb);
  }

  // ---- hoisted cross-attn K/V for all 6 decoder layers (encb is fixed) ----
  gemm_bt<128, 64, 0, true, false><<<dim3(16, 16, 6), 256, 0, stream>>>(
      encb, 512, 0, 0, dcaQKV + (long)512 * 512, 512, (long)1536 * 512, 0,
      dcaKVb, 1024, (long)2048 * 1024, 0, in_f[29], in_f[31], nullptr,
      512, 512, 1, 1.f);

  // ================= decoder =================
  embed_ln<<<rows, 256, 0, stream>>>(tgt, tgt_emb, x, h);
  for (int i = 0; i < C_L; ++i) {
    const long oW = (long)i * 1536 * 512, oB = (long)i * 512;
    // self-attn (reference quirk: src_mask)
    gemm_bt<128, 64, 0, true, false><<<dim3(24, 16, 1), 256, 0, stream>>>(
        h, 512, 0, 0, dsaQKV + oW, 512, 0, 0, qkv, 1536, 0, 0,
        in_f[19] + oB, in_f[21] + oB, in_f[23] + oB, 0, 512, 1, 1.f);
    flash_attn<0><<<dim3(64, 16), 256, 0, stream>>>(qkv, qkv + 512, selfKVB,
                                                    1536, src_mask, ob);
    attn_out(dsaWoT + (long)i * 512 * 512, in_f[25] + oB);
    ln_kernel<<<rows, 256, 0, stream>>>(x, h);
    // cross-attn (reference quirk: tgt_mask = causal); K/V hoisted
    gemm_bt<64, 64, 0, false, false><<<dim3(8, 32, 1), 256, 0, stream>>>(
        h, 512, 0, 0, dcaQKV + oW, 512, 0, 0, qkv, 1536, 0, 0,
        in_f[27] + oB, nullptr, nullptr, 0, 512, 1, 1.f);
    flash_attn<1><<<dim3(64, 16), 256, 0, stream>>>(
        qkv, dcaKVb + (long)i * 2048 * 1024, (long)1024 * 1024, 1024, nullptr,
        ob);
    attn_out(dcaWoT + (long)i * 512 * 512, in_f[33] + oB);
    ln_kernel<<<rows, 256, 0, stream>>>(x, h);
    ffn(decW1T + (long)i * 2048 * 512, in_f[35] + (long)i * 2048,
        decW2T + (long)i * 2048 * 512, in_f[37] + oB);
    ln_kernel<<<rows, 256, 0, stream>>>(x, h);
  }

  // ---- final projection (SWAP grid: M-major for proj_w L2 reuse) ----
  gemm_bt<128, 128, 3, false, true><<<dim3(16, 250, 1), 256, 0, stream>>>(
      h, 512, 0, 0, projT, 512, 0, 0, out, 32000, 0, 0, in_f[39], nullptr,
      nullptr, 0, 512, 1, 1.f);
  logsoftmax_kernel<<<rows, 256, 0, stream>>>(out);
}